// Round 10
// baseline (623.583 us; speedup 1.0000x reference)
//
#include <hip/hip_runtime.h>

static constexpr int NN = 131072;   // nodes
static constexpr int NE = 524288;   // edges
static constexpr int NG = 4096;     // graphs

typedef __attribute__((ext_vector_type(8))) short short8;
typedef __attribute__((ext_vector_type(4))) float f32x4;
typedef __attribute__((ext_vector_type(2))) float f32x2;

__device__ __forceinline__ float bfbits2f(unsigned b) {
    return __uint_as_float(b << 16);
}
__device__ __forceinline__ unsigned short f2bfbits(float f) {
    unsigned u = __float_as_uint(f);
    u += 0x7fffu + ((u >> 16) & 1u);   // RNE
    return (unsigned short)(u >> 16);
}
__device__ __forceinline__ unsigned pack2(float a, float b) {
    return (unsigned)f2bfbits(a) | ((unsigned)f2bfbits(b) << 16);
}

// dual-width integer read (robust to int32 or int64 index tensors)
__device__ __forceinline__ int geti(const void* p, size_t i, int w64) {
    return w64 ? (int)((const long long*)p)[i] : ((const int*)p)[i];
}
// inline int-width detect (sentinel words are chip-wide cached; ~free per thread)
__device__ __forceinline__ int e64_of(const void* eidx) {
    const int* e = (const int*)eidx;
    return (e[1] == 0 && e[2001] == 0 && e[40001] == 0 && e[2 * NE - 1] == 0) ? 1 : 0;
}
__device__ __forceinline__ int b64_of(const void* batch) {
    return (((const int*)batch)[NN - 1] == 0) ? 1 : 0;
}

#if __has_builtin(__builtin_amdgcn_cvt_pk_f32_fp8) && __has_builtin(__builtin_amdgcn_cvt_pk_fp8_f32)
#define FP8_CVT_HW 1
#else
#define FP8_CVT_HW 0
#endif

// ---- software OCP e4m3 codec (fallback) ----
__device__ __forceinline__ float e4m32f(unsigned b) {
    unsigned e = (b >> 3) & 0xFu, m = b & 7u;
    float v = e ? __uint_as_float(((e + 120u) << 23) | (m << 20))
                : (float)m * 0.001953125f;            // m * 2^-9
    return (b & 0x80u) ? -v : v;
}
__device__ __forceinline__ unsigned f2e4m3(float f) {
    unsigned u = __float_as_uint(f);
    unsigned s = (u >> 24) & 0x80u;
    unsigned mag = u & 0x7fffffffu;
    if (mag >= 0x43e00000u) return s | 0x7eu;          // clamp to +-448
    if (mag < 0x3c800000u) {                           // |f| < 2^-6 -> subnormal
        int q = (int)(__uint_as_float(mag) * 512.0f + 0.5f);   // 0..8
        return s | (unsigned)q;
    }
    unsigned r = mag + 0x0007ffffu + ((mag >> 20) & 1u);       // RNE to 3 mant bits
    if (r >= 0x43e00000u) return s | 0x7eu;
    return s | (((r >> 23) - 120u) << 3) | ((r >> 20) & 7u);
}

// 2 fp8 (byte pair HI of dword w) -> packed bf16 dword. HI must be immediate.
template<bool HI>
__device__ __forceinline__ unsigned dec_pair(unsigned w) {
#if FP8_CVT_HW
    f32x2 p = __builtin_amdgcn_cvt_pk_f32_fp8((int)w, HI);
    return __builtin_amdgcn_perm(__float_as_uint(p.y), __float_as_uint(p.x), 0x07060302u);
#else
    unsigned b0 = HI ? ((w >> 16) & 255u) : (w & 255u);
    unsigned b1 = HI ? (w >> 24) : ((w >> 8) & 255u);
    return pack2(e4m32f(b0), e4m32f(b1));
#endif
}

// 8 fp8 -> short8 bf16 fragment
__device__ __forceinline__ short8 dec8(uint2 u) {
    union { uint4 q; short8 s; } r;
    r.q.x = dec_pair<false>(u.x);
    r.q.y = dec_pair<true>(u.x);
    r.q.z = dec_pair<false>(u.y);
    r.q.w = dec_pair<true>(u.y);
    return r.s;
}

// 4 fp8 bytes of dword w -> 4 floats
__device__ __forceinline__ void dec4f(unsigned w, float* v) {
#if FP8_CVT_HW
    f32x2 a = __builtin_amdgcn_cvt_pk_f32_fp8((int)w, false);
    f32x2 b = __builtin_amdgcn_cvt_pk_f32_fp8((int)w, true);
    v[0] = a.x; v[1] = a.y; v[2] = b.x; v[3] = b.y;
#else
#pragma unroll
    for (int i = 0; i < 4; ++i) v[i] = e4m32f((w >> (8 * i)) & 0xffu);
#endif
}

__device__ __forceinline__ unsigned enc4(float a, float b, float c, float d) {
#if FP8_CVT_HW
    int r = __builtin_amdgcn_cvt_pk_fp8_f32(a, b, 0, false);
    r = __builtin_amdgcn_cvt_pk_fp8_f32(c, d, r, true);
    return (unsigned)r;
#else
    return f2e4m3(a) | (f2e4m3(b) << 8) | (f2e4m3(c) << 16) | (f2e4m3(d) << 24);
#endif
}
__device__ __forceinline__ unsigned enc1(float a) {
#if FP8_CVT_HW
    return (unsigned)__builtin_amdgcn_cvt_pk_fp8_f32(a, a, 0, false) & 0xffu;
#else
    return f2e4m3(a);
#endif
}

// async global->LDS, 16B/lane; data lands at l + lane*16
__device__ __forceinline__ void gld16(const void* g, void* l, int lane) {
#if __has_builtin(__builtin_amdgcn_global_load_lds)
    __builtin_amdgcn_global_load_lds((const __attribute__((address_space(1))) unsigned int*)g,
                                     (__attribute__((address_space(3))) unsigned int*)l, 16, 0, 0);
#else
    *(uint4*)((char*)l + lane * 16) = *(const uint4*)g;
#endif
}

// ---------------- merged prep kernel (transposes + bn + zero + gstart) ----------------
__global__ __launch_bounds__(256) void k_prep(
    const float* __restrict__ W1, const float* __restrict__ W2, const float* __restrict__ W3,
    const float* __restrict__ Wf1, const float* __restrict__ Wf2,
    unsigned short* __restrict__ Wt1, unsigned short* __restrict__ Wt2,
    unsigned short* __restrict__ Wt3, unsigned short* __restrict__ Wtf1,
    unsigned short* __restrict__ Wtf2,
    const float* __restrict__ g1, const float* __restrict__ be1,
    const float* __restrict__ m1, const float* __restrict__ v1,
    const float* __restrict__ g2, const float* __restrict__ be2,
    const float* __restrict__ m2, const float* __restrict__ v2,
    const float* __restrict__ g3, const float* __restrict__ be3,
    const float* __restrict__ m3, const float* __restrict__ v3,
    float* __restrict__ sbuf, int* __restrict__ cnt2,
    const void* __restrict__ batch, int* __restrict__ gstart)
{
    const int id = blockIdx.x, tid = threadIdx.x;
    if (id < 1024) {                         // W2 [512,512]
        int idx = id * 256 + tid; int k = idx >> 9, n = idx & 511;
        Wt2[n * 512 + k] = f2bfbits(W2[idx]);
    } else if (id < 1536) {                  // W3 [512,256]
        int idx = (id - 1024) * 256 + tid; int k = idx >> 8, n = idx & 255;
        Wt3[n * 512 + k] = f2bfbits(W3[idx]);
    } else if (id < 1792) {                  // W1 [128,512]
        int idx = (id - 1536) * 256 + tid; int k = idx >> 9, n = idx & 511;
        Wt1[n * 128 + k] = f2bfbits(W1[idx]);
    } else if (id < 2048) {                  // Wf1 [256,256]
        int idx = (id - 1792) * 256 + tid; int k = idx >> 8, n = idx & 255;
        Wtf1[n * 256 + k] = f2bfbits(Wf1[idx]);
    } else if (id < 2304) {                  // Wf2 [256,256]
        int idx = (id - 2048) * 256 + tid; int k = idx >> 8, n = idx & 255;
        Wtf2[n * 256 + k] = f2bfbits(Wf2[idx]);
    } else if (id < 3328) {                  // zero cnt + fillp (contiguous 2*NN ints)
        cnt2[(id - 2304) * 256 + tid] = 0;
    } else if (id < 3333) {                  // bn prep: 512+512+256 channels
        int i = (id - 3328) * 256 + tid;
        if (i < 512) {
            float inv = rsqrtf(v1[i] + 1e-5f); float sc = g1[i] * inv;
            sbuf[i] = sc; sbuf[512 + i] = be1[i] - m1[i] * sc;
        } else if (i < 1024) {
            int j = i - 512;
            float inv = rsqrtf(v2[j] + 1e-5f); float sc = g2[j] * inv;
            sbuf[1024 + j] = sc; sbuf[1536 + j] = be2[j] - m2[j] * sc;
        } else if (i < 1280) {
            int j = i - 1024;
            float inv = rsqrtf(v3[j] + 1e-5f); float sc = g3[j] * inv;
            sbuf[2048 + j] = sc; sbuf[2304 + j] = be3[j] - m3[j] * sc;
        }
    } else {                                 // gstart (batch sorted)
        int i = (id - 3333) * 256 + tid;
        if (i >= NN) return;
        int b64 = b64_of(batch);
        int b = geti(batch, (size_t)i, b64);
        if (i == 0) {
            for (int g = 0; g <= b; ++g) gstart[g] = 0;
        } else {
            int pb = geti(batch, (size_t)i - 1, b64);
            for (int g = pb + 1; g <= b; ++g) gstart[g] = i;
        }
        if (i == NN - 1) {
            for (int g = b + 1; g <= NG; ++g) gstart[g] = NN;
        }
    }
}

__global__ void k_deg_count(const void* __restrict__ eidx, int* __restrict__ cnt) {
    int i = blockIdx.x * 256 + threadIdx.x;
    if (i >= NE) return;
    int d = geti(eidx, (size_t)NE + i, e64_of(eidx));
    atomicAdd(&cnt[d], 1);
}

// single-block exclusive scan of cnt[NN] -> rowptr[NN+1]; fused dinv = rsqrt(cnt+1)
__global__ __launch_bounds__(1024) void k_scan(const int* __restrict__ cnt, int* __restrict__ rowptr,
                                               float* __restrict__ dinv) {
    __shared__ int part[1024];
    const int t = threadIdx.x;
    const int base = t * 128;
    const int4* c4 = (const int4*)(cnt + base);
    int s = 0;
#pragma unroll
    for (int i = 0; i < 32; ++i) { int4 u = c4[i]; s += u.x + u.y + u.z + u.w; }
    part[t] = s;
    __syncthreads();
    for (int off = 1; off < 1024; off <<= 1) {
        int v = (t >= off) ? part[t - off] : 0;
        __syncthreads();
        part[t] += v;
        __syncthreads();
    }
    int ex = (t == 0) ? 0 : part[t - 1];
#pragma unroll
    for (int i = 0; i < 32; ++i) {
        int4 u = c4[i];
        int4 o; o.x = ex; o.y = ex + u.x; o.z = o.y + u.y; o.w = o.z + u.z; ex = o.w + u.w;
        *(int4*)(rowptr + base + 4 * i) = o;
        float4 dv;
        dv.x = rsqrtf((float)(u.x + 1)); dv.y = rsqrtf((float)(u.y + 1));
        dv.z = rsqrtf((float)(u.z + 1)); dv.w = rsqrtf((float)(u.w + 1));
        *(float4*)(dinv + base + 4 * i) = dv;
    }
    if (t == 1023) rowptr[NN] = ex;
}

__global__ void k_fill(const void* __restrict__ eidx,
                       const int* __restrict__ rowptr, int* __restrict__ fillp,
                       int* __restrict__ col) {
    int i = blockIdx.x * 256 + threadIdx.x;
    if (i >= NE) return;
    int e64 = e64_of(eidx);
    int s = geti(eidx, (size_t)i, e64);
    int d = geti(eidx, (size_t)NE + i, e64);
    int p = rowptr[d] + atomicAdd(&fillp[d], 1);
    col[p] = s;
}

// ---------------- half-wave row load/store (16B/lane load, 32 lanes per row) ----------------
template<int D, int MODE>
__device__ __forceinline__ void load_row_hw(const void* h, int sn, int c0, float* v) {
    if constexpr (MODE == 2) {                       // fp32, EPL=4
        float4 u = *(const float4*)((const float*)h + (size_t)sn * D + c0);
        v[0] = u.x; v[1] = u.y; v[2] = u.z; v[3] = u.w;
    } else {                                         // fp8, EPL=16
        uint4 u = *(const uint4*)((const unsigned char*)h + (size_t)sn * D + c0);
        dec4f(u.x, v); dec4f(u.y, v + 4); dec4f(u.z, v + 8); dec4f(u.w, v + 12);
    }
}

template<int D, int EPL, bool FP8>
__device__ __forceinline__ void store_row_hw(void* out, int n, int c0, const float* v) {
    if constexpr (FP8) {                             // EPL=16 -> 16B fp8
        uint4 u;
        u.x = enc4(v[0], v[1], v[2], v[3]);
        u.y = enc4(v[4], v[5], v[6], v[7]);
        u.z = enc4(v[8], v[9], v[10], v[11]);
        u.w = enc4(v[12], v[13], v[14], v[15]);
        *(uint4*)((unsigned char*)out + (size_t)n * D + c0) = u;
    } else {                                         // bf16, EPL=4 -> 8B
        uint2 u; u.x = pack2(v[0], v[1]); u.y = pack2(v[2], v[3]);
        *(uint2*)((unsigned short*)out + (size_t)n * D + c0) = u;
    }
}

// ---------------- half-wave pull aggregation (CSR, fp32 reg accum, 2-edge unrolled) ----------------
template<int D, int IN_MODE, bool OUT_FP8>
__global__ __launch_bounds__(256) void k_agg_hw(
    const void* __restrict__ h,
    const int* __restrict__ rowptr, const int* __restrict__ col,
    const float* __restrict__ dinv,
    void* __restrict__ out)
{
    constexpr int EPL = (IN_MODE == 1) ? 16 : 4;
    const int n = (blockIdx.x * 256 + threadIdx.x) >> 5;
    const int lane = threadIdx.x & 31;
    const int c0 = lane * EPL;
    float dn = dinv[n];
    float acc[EPL], va[EPL], vb[EPL];

    load_row_hw<D, IN_MODE>(h, n, c0, va);    // self loop: weight dinv[n]^2
    float wsl = dn * dn;
#pragma unroll
    for (int i = 0; i < EPL; ++i) acc[i] = va[i] * wsl;

    int e = rowptr[n], e1 = rowptr[n + 1];
    for (; e + 2 <= e1; e += 2) {
        int sa = col[e], sb = col[e + 1];
        float wa = dinv[sa] * dn, wb = dinv[sb] * dn;
        load_row_hw<D, IN_MODE>(h, sa, c0, va);
        load_row_hw<D, IN_MODE>(h, sb, c0, vb);
#pragma unroll
        for (int i = 0; i < EPL; ++i) acc[i] += va[i] * wa + vb[i] * wb;
    }
    if (e < e1) {
        int sa = col[e];
        float wa = dinv[sa] * dn;
        load_row_hw<D, IN_MODE>(h, sa, c0, va);
#pragma unroll
        for (int i = 0; i < EPL; ++i) acc[i] += va[i] * wa;
    }
    store_row_hw<D, EPL, OUT_FP8>(out, n, c0, acc);
}

// ---------------- fused layer-3 aggregation + epilogue + mean pool ----------------
__global__ __launch_bounds__(256) void k_agg_pool(
    const unsigned short* __restrict__ T3,
    const int* __restrict__ rowptr, const int* __restrict__ col,
    const float* __restrict__ dinv,
    const float* __restrict__ b, const float* __restrict__ s, const float* __restrict__ t,
    const int* __restrict__ gstart, unsigned short* __restrict__ pooled)
{
    __shared__ float red[4][256];
    const int g = blockIdx.x;
    const int wave = threadIdx.x >> 6, lane = threadIdx.x & 63;
    const int c0 = lane * 4;
    const int r0 = gstart[g], r1 = gstart[g + 1];
    float p0 = 0, p1 = 0, p2 = 0, p3 = 0;
    const float bc0 = b[c0], bc1 = b[c0 + 1], bc2 = b[c0 + 2], bc3 = b[c0 + 3];
    const float sc0 = s[c0], sc1 = s[c0 + 1], sc2 = s[c0 + 2], sc3 = s[c0 + 3];
    const float tc0 = t[c0], tc1 = t[c0 + 1], tc2 = t[c0 + 2], tc3 = t[c0 + 3];

    for (int n = r0 + wave; n < r1; n += 4) {
        float dn = dinv[n];
        float a0, a1, a2, a3;
        {
            uint2 u = *(const uint2*)(T3 + (size_t)n * 256 + c0);
            float w = dn * dn;
            a0 = bfbits2f(u.x & 0xffffu) * w; a1 = bfbits2f(u.x >> 16) * w;
            a2 = bfbits2f(u.y & 0xffffu) * w; a3 = bfbits2f(u.y >> 16) * w;
        }
        int e = rowptr[n], e1 = rowptr[n + 1];
        for (; e + 2 <= e1; e += 2) {
            int sa = col[e], sb = col[e + 1];
            float wa = dinv[sa] * dn, wb = dinv[sb] * dn;
            uint2 ua = *(const uint2*)(T3 + (size_t)sa * 256 + c0);
            uint2 ub = *(const uint2*)(T3 + (size_t)sb * 256 + c0);
            a0 += bfbits2f(ua.x & 0xffffu) * wa + bfbits2f(ub.x & 0xffffu) * wb;
            a1 += bfbits2f(ua.x >> 16) * wa + bfbits2f(ub.x >> 16) * wb;
            a2 += bfbits2f(ua.y & 0xffffu) * wa + bfbits2f(ub.y & 0xffffu) * wb;
            a3 += bfbits2f(ua.y >> 16) * wa + bfbits2f(ub.y >> 16) * wb;
        }
        if (e < e1) {
            int sa = col[e];
            float wa = dinv[sa] * dn;
            uint2 ua = *(const uint2*)(T3 + (size_t)sa * 256 + c0);
            a0 += bfbits2f(ua.x & 0xffffu) * wa; a1 += bfbits2f(ua.x >> 16) * wa;
            a2 += bfbits2f(ua.y & 0xffffu) * wa; a3 += bfbits2f(ua.y >> 16) * wa;
        }
        // bn3(relu(a + b3))
        p0 += sc0 * fmaxf(a0 + bc0, 0.0f) + tc0;
        p1 += sc1 * fmaxf(a1 + bc1, 0.0f) + tc1;
        p2 += sc2 * fmaxf(a2 + bc2, 0.0f) + tc2;
        p3 += sc3 * fmaxf(a3 + bc3, 0.0f) + tc3;
    }
    red[wave][c0] = p0; red[wave][c0 + 1] = p1; red[wave][c0 + 2] = p2; red[wave][c0 + 3] = p3;
    __syncthreads();
    int ch = threadIdx.x;
    float tot = red[0][ch] + red[1][ch] + red[2][ch] + red[3][ch];
    __syncthreads();
    red[0][ch] = tot;
    __syncthreads();
    if (ch < 128) {
        int ccount = r1 - r0;
        float inv = 1.0f / (float)(ccount > 0 ? ccount : 1);
        pooled[(size_t)g * 256 + 2 * ch] = f2bfbits(red[0][2 * ch] * inv);
        pooled[(size_t)g * 256 + 2 * ch + 1] = f2bfbits(red[0][2 * ch + 1] * inv);
    }
}

// ---------------- MFMA GEMM (4-wave 128x128; MLP head; round-6-proven) ----------------
template<bool A_FP8, int CB, int OUT_MODE, bool RELU, bool HAS_BN, bool HAS_BIAS>
__global__ __launch_bounds__(256)
void k_gemm(const void* __restrict__ Aptr,
            const unsigned short* __restrict__ Wt,
            const float* __restrict__ bias,
            const float* __restrict__ s, const float* __restrict__ t,
            void* __restrict__ Cptr,
            int K, int Ncols)
{
    __shared__ __align__(16) unsigned short lB[2][2][128 * 32];
    __shared__ __align__(16) unsigned char  lA8[A_FP8 ? 2 : 1][A_FP8 ? 2 : 1][A_FP8 ? 128 * 32 : 16];
    __shared__ __align__(16) unsigned short lA16[A_FP8 ? 1 : 2][A_FP8 ? 1 : 2][A_FP8 ? 8 : 128 * 32];
    const int tid = threadIdx.x;
    const int id = blockIdx.x;
    const int hi = id >> 3;
    const int cblk = hi % CB;
    const int rblk = (hi / CB) * 8 + (id & 7);
    const int bm = rblk * 128;
    const int bn = cblk * 128;
    const int lane = tid & 63;
    const int wave = tid >> 6;
    const int wm = (wave >> 1) * 64;
    const int wn = (wave & 1) * 64;
    const int fr = lane & 15;
    const int fq = lane >> 4;

    f32x4 acc[4][4] = {};
    const int NG64 = K >> 6;

    auto stage = [&](int buf, int k0) {
#pragma unroll
        for (int h = 0; h < 2; ++h) {
            const int kh = k0 + h * 32;
            if constexpr (A_FP8) {
                const unsigned char* g = (const unsigned char*)Aptr
                    + (size_t)(bm + (wave << 5) + (lane >> 1)) * K + kh + (lane & 1) * 16;
                gld16(g, &lA8[buf][h][(wave << 5) * 32], lane);
            } else {
                const unsigned short* Ab = (const unsigned short*)Aptr;
#pragma unroll
                for (int c = 0; c < 2; ++c) {
                    const unsigned short* g = Ab
                        + (size_t)(bm + (wave << 5) + (c << 4) + (lane >> 2)) * K + kh + (lane & 3) * 8;
                    gld16(g, &lA16[buf][h][((wave << 5) + (c << 4)) * 32], lane);
                }
            }
#pragma unroll
            for (int c = 0; c < 2; ++c) {
                const unsigned short* g = Wt
                    + (size_t)(bn + (wave << 5) + (c << 4) + (lane >> 2)) * K + kh + (lane & 3) * 8;
                gld16(g, &lB[buf][h][((wave << 5) + (c << 4)) * 32], lane);
            }
        }
    };

    stage(0, 0);
    __syncthreads();

    int cur = 0;
    for (int kg = 0; kg < NG64; ++kg) {
        if (kg + 1 < NG64) stage(cur ^ 1, (kg + 1) << 6);

#pragma unroll
        for (int h = 0; h < 2; ++h) {
            short8 a[4], b[4];
#pragma unroll
            for (int i = 0; i < 4; ++i) {
                if constexpr (A_FP8)
                    a[i] = dec8(*(const uint2*)&lA8[cur][h][(wm + 16 * i + fr) * 32 + fq * 8]);
                else
                    a[i] = *(const short8*)&lA16[cur][h][(wm + 16 * i + fr) * 32 + fq * 8];
            }
#pragma unroll
            for (int j = 0; j < 4; ++j)
                b[j] = *(const short8*)&lB[cur][h][(wn + 16 * j + fr) * 32 + fq * 8];
#pragma unroll
            for (int i = 0; i < 4; ++i)
#pragma unroll
                for (int j = 0; j < 4; ++j)
                    acc[i][j] = __builtin_amdgcn_mfma_f32_16x16x32_bf16(a[i], b[j], acc[i][j], 0, 0, 0);
        }

        __syncthreads();
        cur ^= 1;
    }

#pragma unroll
    for (int j = 0; j < 4; ++j) {
        int colI = bn + wn + 16 * j + fr;
        float bi = HAS_BIAS ? bias[colI] : 0.0f;
        float sc = HAS_BN ? s[colI] : 1.0f;
        float tc = HAS_BN ? t[colI] : 0.0f;
#pragma unroll
        for (int i = 0; i < 4; ++i) {
#pragma unroll
            for (int r = 0; r < 4; ++r) {
                int row = bm + wm + 16 * i + fq * 4 + r;
                float z = acc[i][j][r] + bi;
                if (RELU) z = fmaxf(z, 0.0f);
                float y = HAS_BN ? (sc * z + tc) : z;
                if constexpr (OUT_MODE == 2)
                    ((float*)Cptr)[(size_t)row * Ncols + colI] = y;
                else if constexpr (OUT_MODE == 1)
                    ((unsigned char*)Cptr)[(size_t)row * Ncols + colI] = (unsigned char)enc1(y);
                else
                    ((unsigned short*)Cptr)[(size_t)row * Ncols + colI] = f2bfbits(y);
            }
        }
    }
}

// ---------------- 8-wave 256x128 fp8-A MFMA GEMM (GEMM2; round-8-proven) ----------------
template<int CB, int OUT_MODE, bool RELU, bool HAS_BN, bool HAS_BIAS>
__global__ __launch_bounds__(512)
void k_gemm8w(const unsigned char* __restrict__ Aptr,
              const unsigned short* __restrict__ Wt,
              const float* __restrict__ bias,
              const float* __restrict__ s, const float* __restrict__ t,
              void* __restrict__ Cptr,
              int K, int Ncols)
{
    __shared__ __align__(16) unsigned char  lA[2][2][256 * 32];   // 32 KB fp8
    __shared__ __align__(16) unsigned short lB[2][2][128 * 32];   // 32 KB bf16
    const int tid = threadIdx.x;
    const int id = blockIdx.x;
    const int hi = id >> 3;
    const int cblk = hi % CB;
    const int rblk = (hi / CB) * 8 + (id & 7);
    const int bm = rblk * 256;
    const int bn = cblk * 128;
    const int lane = tid & 63;
    const int wave = tid >> 6;          // 0..7
    const int wm = (wave >> 1) * 64;    // 0,64,128,192
    const int wn = (wave & 1) * 64;     // 0,64
    const int fr = lane & 15;
    const int fq = lane >> 4;

    f32x4 acc[4][4] = {};
    const int NG64 = K >> 6;

    auto stage = [&](int buf, int k0) {
#pragma unroll
        for (int h = 0; h < 2; ++h) {
            const int kh = k0 + h * 32;
            {
                const unsigned char* g = Aptr
                    + (size_t)(bm + (wave << 5) + (lane >> 1)) * K + kh + (lane & 1) * 16;
                gld16(g, &lA[buf][h][(wave << 5) * 32], lane);
            }
            {
                const unsigned short* g = Wt
                    + (size_t)(bn + (wave << 4) + (lane >> 2)) * K + kh + (lane & 3) * 8;
                gld16(g, &lB[buf][h][(wave << 4) * 32], lane);
            }
        }
    };

    stage(0, 0);
    __syncthreads();

    int cur = 0;
    for (int kg = 0; kg < NG64; ++kg) {
        if (kg + 1 < NG64) stage(cur ^ 1, (kg + 1) << 6);

#pragma unroll
        for (int h = 0; h < 2; ++h) {
            short8 a[4], b[4];
#pragma unroll
            for (int i = 0; i < 4; ++i)
                a[i] = dec8(*(const uint2*)&lA[cur][h][(wm + 16 * i + fr) * 32 + fq * 8]);
#pragma unroll
            for (int j = 0; j < 4; ++j)
                b[j] = *(const short8*)&lB[cur][h][(wn + 16 * j + fr) * 32 + fq * 8];
#pragma unroll
            for (int i = 0; i < 4; ++i)
#pragma unroll
                for (int j = 0; j < 4; ++j)
                    acc[i][j] = __builtin_amdgcn_mfma_f32_16x16x32_bf16(a[i], b[j], acc[i][j], 0, 0, 0);
        }

        __syncthreads();
        cur ^= 1;
    }

#pragma unroll
    for (int j = 0; j < 4; ++j) {
        int colI = bn + wn + 16 * j + fr;
        float bi = HAS_BIAS ? bias[colI] : 0.0f;
        float sc = HAS_BN ? s[colI] : 1.0f;
        float tc = HAS_BN ? t[colI] : 0.0f;
#pragma unroll
        for (int i = 0; i < 4; ++i) {
#pragma unroll
            for (int r = 0; r < 4; ++r) {
                int row = bm + wm + 16 * i + fq * 4 + r;
                float z = acc[i][j][r] + bi;
                if (RELU) z = fmaxf(z, 0.0f);
                float y = HAS_BN ? (sc * z + tc) : z;
                if constexpr (OUT_MODE == 2)
                    ((float*)Cptr)[(size_t)row * Ncols + colI] = y;
                else if constexpr (OUT_MODE == 1)
                    ((unsigned char*)Cptr)[(size_t)row * Ncols + colI] = (unsigned char)enc1(y);
                else
                    ((unsigned short*)Cptr)[(size_t)row * Ncols + colI] = f2bfbits(y);
            }
        }
    }
}

// ---------------- 8-wave 128x128 fp8-A, small-acc MFMA GEMM (GEMM3 guinea pig) ----------------
// Register-occupancy variant: acc[2][4] (32 regs) + __launch_bounds__(512,6) caps VGPR at 85
// -> 6 waves/SIMD = 24 waves/CU target (vs 16 reg-capped in k_gemm8w). LDS 48 KB -> 3 blocks/CU.
// A staged by wave-quartets (waves 0-3 stage half 0, 4-7 half 1). Bit-identical math.
template<int CB, int OUT_MODE, bool RELU, bool HAS_BN, bool HAS_BIAS>
__global__ __launch_bounds__(512, 6)
void k_gemm8f(const unsigned char* __restrict__ Aptr,
              const unsigned short* __restrict__ Wt,
              const float* __restrict__ bias,
              const float* __restrict__ s, const float* __restrict__ t,
              void* __restrict__ Cptr,
              int K, int Ncols)
{
    __shared__ __align__(16) unsigned char  lA[2][2][128 * 32];   // 16 KB fp8
    __shared__ __align__(16) unsigned short lB[2][2][128 * 32];   // 32 KB bf16
    const int tid = threadIdx.x;
    const int id = blockIdx.x;
    const int hi = id >> 3;
    const int cblk = hi % CB;
    const int rblk = (hi / CB) * 8 + (id & 7);
    const int bm = rblk * 128;
    const int bn = cblk * 128;
    const int lane = tid & 63;
    const int wave = tid >> 6;          // 0..7
    const int wm = (wave >> 1) * 32;    // 0,32,64,96
    const int wn = (wave & 1) * 64;     // 0,64
    const int fr = lane & 15;
    const int fq = lane >> 4;

    f32x4 acc[2][4] = {};
    const int NG64 = K >> 6;

    const int ah  = wave >> 2;          // which 32-wide half this wave stages for A
    const int arb = (wave & 3) << 5;    // A row base (32 rows per wave)

    auto stage = [&](int buf, int k0) {
        // A fp8: rows arb..arb+31, 32B each (one 32-wide half per wave)
        const unsigned char* ga = Aptr
            + (size_t)(bm + arb + (lane >> 1)) * K + k0 + ah * 32 + (lane & 1) * 16;
        gld16(ga, &lA[buf][ah][arb * 32], lane);
        // B bf16: all 8 waves, both halves (16 rows x 32 elems per wave per half)
#pragma unroll
        for (int h = 0; h < 2; ++h) {
            const unsigned short* gb = Wt
                + (size_t)(bn + (wave << 4) + (lane >> 2)) * K + k0 + h * 32 + (lane & 3) * 8;
            gld16(gb, &lB[buf][h][(wave << 4) * 32], lane);
        }
    };

    stage(0, 0);
    __syncthreads();

    int cur = 0;
    for (int kg = 0; kg < NG64; ++kg) {
        if (kg + 1 < NG64) stage(cur ^ 1, (kg + 1) << 6);

#pragma unroll
        for (int h = 0; h < 2; ++h) {
            short8 a[2], b[4];
#pragma unroll
            for (int i = 0; i < 2; ++i)
                a[i] = dec8(*(const uint2*)&lA[cur][h][(wm + 16 * i + fr) * 32 + fq * 8]);
#pragma unroll
            for (int j = 0; j < 4; ++j)
                b[j] = *(const short8*)&lB[cur][h][(wn + 16 * j + fr) * 32 + fq * 8];
#pragma unroll
            for (int i = 0; i < 2; ++i)
#pragma unroll
                for (int j = 0; j < 4; ++j)
                    acc[i][j] = __builtin_amdgcn_mfma_f32_16x16x32_bf16(a[i], b[j], acc[i][j], 0, 0, 0);
        }

        __syncthreads();
        cur ^= 1;
    }

#pragma unroll
    for (int j = 0; j < 4; ++j) {
        int colI = bn + wn + 16 * j + fr;
        float bi = HAS_BIAS ? bias[colI] : 0.0f;
        float sc = HAS_BN ? s[colI] : 1.0f;
        float tc = HAS_BN ? t[colI] : 0.0f;
#pragma unroll
        for (int i = 0; i < 2; ++i) {
#pragma unroll
            for (int r = 0; r < 4; ++r) {
                int row = bm + wm + 16 * i + fq * 4 + r;
                float z = acc[i][j][r] + bi;
                if (RELU) z = fmaxf(z, 0.0f);
                float y = HAS_BN ? (sc * z + tc) : z;
                if constexpr (OUT_MODE == 2)
                    ((float*)Cptr)[(size_t)row * Ncols + colI] = y;
                else if constexpr (OUT_MODE == 1)
                    ((unsigned char*)Cptr)[(size_t)row * Ncols + colI] = (unsigned char)enc1(y);
                else
                    ((unsigned short*)Cptr)[(size_t)row * Ncols + colI] = f2bfbits(y);
            }
        }
    }
}

// ---------------- 8-wave 128x128 bf16-A MFMA GEMM (GEMM1; round-9-proven) ----------------
template<int CB, int OUT_MODE, bool RELU, bool HAS_BN, bool HAS_BIAS>
__global__ __launch_bounds__(512)
void k_gemm8n(const unsigned short* __restrict__ Aptr,
              const unsigned short* __restrict__ Wt,
              const float* __restrict__ bias,
              const float* __restrict__ s, const float* __restrict__ t,
              void* __restrict__ Cptr,
              int K, int Ncols)
{
    __shared__ __align__(16) unsigned short lA[2][2][128 * 32];   // 32 KB
    __shared__ __align__(16) unsigned short lB[2][2][128 * 32];   // 32 KB
    const int tid = threadIdx.x;
    const int id = blockIdx.x;
    const int hi = id >> 3;
    const int cblk = hi % CB;
    const int rblk = (hi / CB) * 8 + (id & 7);
    const int bm = rblk * 128;
    const int bn = cblk * 128;
    const int lane = tid & 63;
    const int wave = tid >> 6;          // 0..7
    const int wm = (wave >> 1) * 32;    // 0,32,64,96
    const int wn = (wave & 1) * 64;     // 0,64
    const int fr = lane & 15;
    const int fq = lane >> 4;

    f32x4 acc[2][4] = {};
    const int NG64 = K >> 6;

    auto stage = [&](int buf, int k0) {
#pragma unroll
        for (int h = 0; h < 2; ++h) {
            const int kh = k0 + h * 32;
            const unsigned short* ga = Aptr
                + (size_t)(bm + (wave << 4) + (lane >> 2)) * K + kh + (lane & 3) * 8;
            gld16(ga, &lA[buf][h][(wave << 4) * 32], lane);
            const unsigned short* gb = Wt
                + (size_t)(bn + (wave << 4) + (lane >> 2)) * K + kh + (lane & 3) * 8;
            gld16(gb, &lB[buf][h][(wave << 4) * 32], lane);
        }
    };

    stage(0, 0);
    __syncthreads();

    int cur = 0;
    for (int kg = 0; kg < NG64; ++kg) {
        if (kg + 1 < NG64) stage(cur ^ 1, (kg + 1) << 6);

#pragma unroll
        for (int h = 0; h < 2; ++h) {
            short8 a[2], b[4];
#pragma unroll
            for (int i = 0; i < 2; ++i)
                a[i] = *(const short8*)&lA[cur][h][(wm + 16 * i + fr) * 32 + fq * 8];
#pragma unroll
            for (int j = 0; j < 4; ++j)
                b[j] = *(const short8*)&lB[cur][h][(wn + 16 * j + fr) * 32 + fq * 8];
#pragma unroll
            for (int i = 0; i < 2; ++i)
#pragma unroll
                for (int j = 0; j < 4; ++j)
                    acc[i][j] = __builtin_amdgcn_mfma_f32_16x16x32_bf16(a[i], b[j], acc[i][j], 0, 0, 0);
        }

        __syncthreads();
        cur ^= 1;
    }

#pragma unroll
    for (int j = 0; j < 4; ++j) {
        int colI = bn + wn + 16 * j + fr;
        float bi = HAS_BIAS ? bias[colI] : 0.0f;
        float sc = HAS_BN ? s[colI] : 1.0f;
        float tc = HAS_BN ? t[colI] : 0.0f;
#pragma unroll
        for (int i = 0; i < 2; ++i) {
#pragma unroll
            for (int r = 0; r < 4; ++r) {
                int row = bm + wm + 16 * i + fq * 4 + r;
                float z = acc[i][j][r] + bi;
                if (RELU) z = fmaxf(z, 0.0f);
                float y = HAS_BN ? (sc * z + tc) : z;
                if constexpr (OUT_MODE == 2)
                    ((float*)Cptr)[(size_t)row * Ncols + colI] = y;
                else if constexpr (OUT_MODE == 1)
                    ((unsigned char*)Cptr)[(size_t)row * Ncols + colI] = (unsigned char)enc1(y);
                else
                    ((unsigned short*)Cptr)[(size_t)row * Ncols + colI] = f2bfbits(y);
            }
        }
    }
}

// ---------------- launch ----------------

extern "C" void kernel_launch(void* const* d_in, const int* in_sizes, int n_in,
                              void* d_out, int out_size, void* d_ws, size_t ws_size,
                              hipStream_t stream) {
    const float* x   = (const float*)d_in[0];      // fp32 per reference
    const void* eidx = d_in[1];
    const void* batch = d_in[2];
    const float* W1  = (const float*)d_in[3];
    const float* b1  = (const float*)d_in[4];
    const float* W2  = (const float*)d_in[5];
    const float* b2  = (const float*)d_in[6];
    const float* W3  = (const float*)d_in[7];
    const float* b3  = (const float*)d_in[8];
    const float* g1  = (const float*)d_in[9];
    const float* be1 = (const float*)d_in[10];
    const float* m1  = (const float*)d_in[11];
    const float* v1  = (const float*)d_in[12];
    const float* g2  = (const float*)d_in[13];
    const float* be2 = (const float*)d_in[14];
    const float* m2  = (const float*)d_in[15];
    const float* v2  = (const float*)d_in[16];
    const float* g3  = (const float*)d_in[17];
    const float* be3 = (const float*)d_in[18];
    const float* m3  = (const float*)d_in[19];
    const float* v3  = (const float*)d_in[20];
    const float* Wf1 = (const float*)d_in[21];
    const float* bf1 = (const float*)d_in[22];
    const float* Wf2 = (const float*)d_in[23];
    const float* bf2 = (const float*)d_in[24];

    // ---- fixed compact layout (round-6-proven, ~139.6 MiB) ----
    unsigned char* RB = (unsigned char*)d_ws;            // 64 MiB: H1/H2 fp8 [NN,512]; later pooled/z1
    unsigned char* RA = RB + 67108864;                   // 64 MiB: agg1 bf16 / agg2 fp8 / T3 bf16
    unsigned char* EX = RB + 134217728;                  // extras ~5.4 MiB
    int*   rowptr = (int*)(EX + 0);
    int*   col    = (int*)(EX + 524544);
    float* dinv   = (float*)(EX + 2621696);
    int*   cnt    = (int*)(EX + 3145984);
    int*   fillp  = (int*)(EX + 3670272);   // contiguous after cnt (cnt is NN ints)
    int*   gstart = (int*)(EX + 4194560);
    float* sbuf   = (float*)(EX + 4211456);
    float *s1 = sbuf, *t1 = sbuf + 512, *s2 = sbuf + 1024, *t2 = sbuf + 1536;
    float *s3 = sbuf + 2048, *t3v = sbuf + 2304;
    unsigned short* Wt1  = (unsigned short*)(EX + 4221696);  // [512,128] bf16
    unsigned short* Wt2  = (unsigned short*)(EX + 4352768);  // [512,512]
    unsigned short* Wt3  = (unsigned short*)(EX + 4877056);  // [256,512]
    unsigned short* Wtf1 = (unsigned short*)(EX + 5139200);  // [256,256]
    unsigned short* Wtf2 = (unsigned short*)(EX + 5270272);  // [256,256]

    unsigned short* pooled = (unsigned short*)RB;            // [NG,256] bf16 (H2 dead after GEMM3)
    unsigned short* z1     = (unsigned short*)(RB + 2097152);

    // ---- prep: single merged kernel, then CSR build ----
    k_prep<<<3845, 256, 0, stream>>>(W1, W2, W3, Wf1, Wf2,
                                     Wt1, Wt2, Wt3, Wtf1, Wtf2,
                                     g1, be1, m1, v1, g2, be2, m2, v2, g3, be3, m3, v3,
                                     sbuf, cnt, batch, gstart);
    k_deg_count<<<NE / 256, 256, 0, stream>>>(eidx, cnt);
    k_scan<<<1, 1024, 0, stream>>>(cnt, rowptr, dinv);
    k_fill<<<NE / 256, 256, 0, stream>>>(eidx, rowptr, fillp, col);

    const dim3 gagg(NN / 8);   // one node per 32-lane half-wave

    // L1: agg x(fp32) @128 -> bf16 agg1 (RA); 8-wave GEMM 128->512 +bias+relu+bn -> H1 fp8 (RB)
    k_agg_hw<128, 2, false><<<gagg, 256, 0, stream>>>(x, rowptr, col, dinv, RA);
    k_gemm8n<4, 1, true, true, true><<<4096, 512, 0, stream>>>(
        (const unsigned short*)RA, Wt1, b1, s1, t1, RB, 128, 512);

    // L2: agg H1(fp8) @512 -> agg2 fp8 (RA); 8-wave GEMM 512->512 +epilogue -> H2 fp8 (RB)
    // split into two row-half dispatches (diagnostic: un-monopolize the top-5 window)
    k_agg_hw<512, 1, true><<<gagg, 256, 0, stream>>>(RB, rowptr, col, dinv, RA);
    k_gemm8w<4, 1, true, true, true><<<1024, 512, 0, stream>>>(RA, Wt2, b2, s2, t2, RB, 512, 512);
    k_gemm8w<4, 1, true, true, true><<<1024, 512, 0, stream>>>(RA + 33554432, Wt2, b2, s2, t2,
                                                               RB + 33554432, 512, 512);

    // L3: 8-wave small-acc GEMM 512->256 raw (H2 fp8 -> T3 bf16 in RA)
    k_gemm8f<2, 0, false, false, false><<<2048, 512, 0, stream>>>(RB, Wt3, nullptr, nullptr, nullptr, RA, 512, 256);

    // fused: agg @256 + bn3(relu(+b3)) + mean pool -> pooled bf16 (RB; H2 dead)
    k_agg_pool<<<NG, 256, 0, stream>>>((const unsigned short*)RA, rowptr, col, dinv,
                                       b3, s3, t3v, gstart, pooled);

    // MLP head: z1 = relu(pooled@Wf1 + bf1); out(fp32) = z1@Wf2 + bf2
    k_gemm<false, 2, 0, true, false, true><<<64, 256, 0, stream>>>(pooled, Wtf1, bf1, nullptr, nullptr, z1, 256, 256);
    k_gemm<false, 2, 2, false, false, true><<<64, 256, 0, stream>>>(z1, Wtf2, bf2, nullptr, nullptr, d_out, 256, 256);
}

// Round 11
// 563.363 us; speedup vs baseline: 1.1069x; 1.1069x over previous
//
#include <hip/hip_runtime.h>

static constexpr int NN = 131072;   // nodes
static constexpr int NE = 524288;   // edges
static constexpr int NG = 4096;     // graphs

typedef __attribute__((ext_vector_type(8))) short short8;
typedef __attribute__((ext_vector_type(4))) float f32x4;
typedef __attribute__((ext_vector_type(2))) float f32x2;

__device__ __forceinline__ float bfbits2f(unsigned b) {
    return __uint_as_float(b << 16);
}
__device__ __forceinline__ unsigned short f2bfbits(float f) {
    unsigned u = __float_as_uint(f);
    u += 0x7fffu + ((u >> 16) & 1u);   // RNE
    return (unsigned short)(u >> 16);
}
__device__ __forceinline__ unsigned pack2(float a, float b) {
    return (unsigned)f2bfbits(a) | ((unsigned)f2bfbits(b) << 16);
}

// dual-width integer read (robust to int32 or int64 index tensors)
__device__ __forceinline__ int geti(const void* p, size_t i, int w64) {
    return w64 ? (int)((const long long*)p)[i] : ((const int*)p)[i];
}
// inline int-width detect (sentinel words are chip-wide cached; ~free per thread)
__device__ __forceinline__ int e64_of(const void* eidx) {
    const int* e = (const int*)eidx;
    return (e[1] == 0 && e[2001] == 0 && e[40001] == 0 && e[2 * NE - 1] == 0) ? 1 : 0;
}
__device__ __forceinline__ int b64_of(const void* batch) {
    return (((const int*)batch)[NN - 1] == 0) ? 1 : 0;
}

#if __has_builtin(__builtin_amdgcn_cvt_pk_f32_fp8) && __has_builtin(__builtin_amdgcn_cvt_pk_fp8_f32)
#define FP8_CVT_HW 1
#else
#define FP8_CVT_HW 0
#endif

// ---- software OCP e4m3 codec (fallback) ----
__device__ __forceinline__ float e4m32f(unsigned b) {
    unsigned e = (b >> 3) & 0xFu, m = b & 7u;
    float v = e ? __uint_as_float(((e + 120u) << 23) | (m << 20))
                : (float)m * 0.001953125f;            // m * 2^-9
    return (b & 0x80u) ? -v : v;
}
__device__ __forceinline__ unsigned f2e4m3(float f) {
    unsigned u = __float_as_uint(f);
    unsigned s = (u >> 24) & 0x80u;
    unsigned mag = u & 0x7fffffffu;
    if (mag >= 0x43e00000u) return s | 0x7eu;          // clamp to +-448
    if (mag < 0x3c800000u) {                           // |f| < 2^-6 -> subnormal
        int q = (int)(__uint_as_float(mag) * 512.0f + 0.5f);   // 0..8
        return s | (unsigned)q;
    }
    unsigned r = mag + 0x0007ffffu + ((mag >> 20) & 1u);       // RNE to 3 mant bits
    if (r >= 0x43e00000u) return s | 0x7eu;
    return s | (((r >> 23) - 120u) << 3) | ((r >> 20) & 7u);
}

// 2 fp8 (byte pair HI of dword w) -> packed bf16 dword. HI must be immediate.
template<bool HI>
__device__ __forceinline__ unsigned dec_pair(unsigned w) {
#if FP8_CVT_HW
    f32x2 p = __builtin_amdgcn_cvt_pk_f32_fp8((int)w, HI);
    return __builtin_amdgcn_perm(__float_as_uint(p.y), __float_as_uint(p.x), 0x07060302u);
#else
    unsigned b0 = HI ? ((w >> 16) & 255u) : (w & 255u);
    unsigned b1 = HI ? (w >> 24) : ((w >> 8) & 255u);
    return pack2(e4m32f(b0), e4m32f(b1));
#endif
}

// 8 fp8 -> short8 bf16 fragment
__device__ __forceinline__ short8 dec8(uint2 u) {
    union { uint4 q; short8 s; } r;
    r.q.x = dec_pair<false>(u.x);
    r.q.y = dec_pair<true>(u.x);
    r.q.z = dec_pair<false>(u.y);
    r.q.w = dec_pair<true>(u.y);
    return r.s;
}

// 4 fp8 bytes of dword w -> 4 floats
__device__ __forceinline__ void dec4f(unsigned w, float* v) {
#if FP8_CVT_HW
    f32x2 a = __builtin_amdgcn_cvt_pk_f32_fp8((int)w, false);
    f32x2 b = __builtin_amdgcn_cvt_pk_f32_fp8((int)w, true);
    v[0] = a.x; v[1] = a.y; v[2] = b.x; v[3] = b.y;
#else
#pragma unroll
    for (int i = 0; i < 4; ++i) v[i] = e4m32f((w >> (8 * i)) & 0xffu);
#endif
}

__device__ __forceinline__ unsigned enc4(float a, float b, float c, float d) {
#if FP8_CVT_HW
    int r = __builtin_amdgcn_cvt_pk_fp8_f32(a, b, 0, false);
    r = __builtin_amdgcn_cvt_pk_fp8_f32(c, d, r, true);
    return (unsigned)r;
#else
    return f2e4m3(a) | (f2e4m3(b) << 8) | (f2e4m3(c) << 16) | (f2e4m3(d) << 24);
#endif
}
__device__ __forceinline__ unsigned enc1(float a) {
#if FP8_CVT_HW
    return (unsigned)__builtin_amdgcn_cvt_pk_fp8_f32(a, a, 0, false) & 0xffu;
#else
    return f2e4m3(a);
#endif
}

// async global->LDS, 16B/lane; data lands at l + lane*16
__device__ __forceinline__ void gld16(const void* g, void* l, int lane) {
#if __has_builtin(__builtin_amdgcn_global_load_lds)
    __builtin_amdgcn_global_load_lds((const __attribute__((address_space(1))) unsigned int*)g,
                                     (__attribute__((address_space(3))) unsigned int*)l, 16, 0, 0);
#else
    *(uint4*)((char*)l + lane * 16) = *(const uint4*)g;
#endif
}

// ---------------- merged prep kernel (transposes + bn + zero + gstart) ----------------
__global__ __launch_bounds__(256) void k_prep(
    const float* __restrict__ W1, const float* __restrict__ W2, const float* __restrict__ W3,
    const float* __restrict__ Wf1, const float* __restrict__ Wf2,
    unsigned short* __restrict__ Wt1, unsigned short* __restrict__ Wt2,
    unsigned short* __restrict__ Wt3, unsigned short* __restrict__ Wtf1,
    unsigned short* __restrict__ Wtf2,
    const float* __restrict__ g1, const float* __restrict__ be1,
    const float* __restrict__ m1, const float* __restrict__ v1,
    const float* __restrict__ g2, const float* __restrict__ be2,
    const float* __restrict__ m2, const float* __restrict__ v2,
    const float* __restrict__ g3, const float* __restrict__ be3,
    const float* __restrict__ m3, const float* __restrict__ v3,
    float* __restrict__ sbuf, int* __restrict__ cnt2,
    const void* __restrict__ batch, int* __restrict__ gstart)
{
    const int id = blockIdx.x, tid = threadIdx.x;
    if (id < 1024) {                         // W2 [512,512]
        int idx = id * 256 + tid; int k = idx >> 9, n = idx & 511;
        Wt2[n * 512 + k] = f2bfbits(W2[idx]);
    } else if (id < 1536) {                  // W3 [512,256]
        int idx = (id - 1024) * 256 + tid; int k = idx >> 8, n = idx & 255;
        Wt3[n * 512 + k] = f2bfbits(W3[idx]);
    } else if (id < 1792) {                  // W1 [128,512]
        int idx = (id - 1536) * 256 + tid; int k = idx >> 9, n = idx & 511;
        Wt1[n * 128 + k] = f2bfbits(W1[idx]);
    } else if (id < 2048) {                  // Wf1 [256,256]
        int idx = (id - 1792) * 256 + tid; int k = idx >> 8, n = idx & 255;
        Wtf1[n * 256 + k] = f2bfbits(Wf1[idx]);
    } else if (id < 2304) {                  // Wf2 [256,256]
        int idx = (id - 2048) * 256 + tid; int k = idx >> 8, n = idx & 255;
        Wtf2[n * 256 + k] = f2bfbits(Wf2[idx]);
    } else if (id < 3328) {                  // zero cnt + fillp (contiguous 2*NN ints)
        cnt2[(id - 2304) * 256 + tid] = 0;
    } else if (id < 3333) {                  // bn prep: 512+512+256 channels
        int i = (id - 3328) * 256 + tid;
        if (i < 512) {
            float inv = rsqrtf(v1[i] + 1e-5f); float sc = g1[i] * inv;
            sbuf[i] = sc; sbuf[512 + i] = be1[i] - m1[i] * sc;
        } else if (i < 1024) {
            int j = i - 512;
            float inv = rsqrtf(v2[j] + 1e-5f); float sc = g2[j] * inv;
            sbuf[1024 + j] = sc; sbuf[1536 + j] = be2[j] - m2[j] * sc;
        } else if (i < 1280) {
            int j = i - 1024;
            float inv = rsqrtf(v3[j] + 1e-5f); float sc = g3[j] * inv;
            sbuf[2048 + j] = sc; sbuf[2304 + j] = be3[j] - m3[j] * sc;
        }
    } else {                                 // gstart (batch sorted)
        int i = (id - 3333) * 256 + tid;
        if (i >= NN) return;
        int b64 = b64_of(batch);
        int b = geti(batch, (size_t)i, b64);
        if (i == 0) {
            for (int g = 0; g <= b; ++g) gstart[g] = 0;
        } else {
            int pb = geti(batch, (size_t)i - 1, b64);
            for (int g = pb + 1; g <= b; ++g) gstart[g] = i;
        }
        if (i == NN - 1) {
            for (int g = b + 1; g <= NG; ++g) gstart[g] = NN;
        }
    }
}

__global__ void k_deg_count(const void* __restrict__ eidx, int* __restrict__ cnt) {
    int i = blockIdx.x * 256 + threadIdx.x;
    if (i >= NE) return;
    int d = geti(eidx, (size_t)NE + i, e64_of(eidx));
    atomicAdd(&cnt[d], 1);
}

// ---------------- 3-phase multi-block scan (replaces 75us single-block k_scan) ----------------
// Phase A: per-block sums over 512-int chunks (256 blocks x 256 thr).
__global__ __launch_bounds__(256) void k_scan_a(const int* __restrict__ cnt, int* __restrict__ bsum) {
    __shared__ int red[256];
    const int t = threadIdx.x;
    int2 u = *(const int2*)(cnt + blockIdx.x * 512 + t * 2);
    red[t] = u.x + u.y;
    __syncthreads();
    for (int off = 128; off > 0; off >>= 1) {
        if (t < off) red[t] += red[t + off];
        __syncthreads();
    }
    if (t == 0) bsum[blockIdx.x] = red[0];
}

// Phase B: 1 block exclusive scan of bsum[256] -> boff[256]; writes rowptr[NN].
__global__ __launch_bounds__(256) void k_scan_b(const int* __restrict__ bsum, int* __restrict__ boff,
                                                int* __restrict__ rowptr) {
    __shared__ int part[256];
    const int t = threadIdx.x;
    int v = bsum[t];
    part[t] = v;
    __syncthreads();
    for (int off = 1; off < 256; off <<= 1) {
        int w = (t >= off) ? part[t - off] : 0;
        __syncthreads();
        part[t] += w;
        __syncthreads();
    }
    boff[t] = part[t] - v;   // exclusive
    if (t == 255) rowptr[NN] = part[255];
}

// Phase C: local exclusive scan per chunk + boff offset -> rowptr; fused dinv = rsqrt(cnt+1).
__global__ __launch_bounds__(256) void k_scan_c(const int* __restrict__ cnt, const int* __restrict__ boff,
                                                int* __restrict__ rowptr, float* __restrict__ dinv) {
    __shared__ int part[256];
    const int t = threadIdx.x;
    const int base = blockIdx.x * 512 + t * 2;
    int2 u = *(const int2*)(cnt + base);
    int s = u.x + u.y;
    part[t] = s;
    __syncthreads();
    for (int off = 1; off < 256; off <<= 1) {
        int w = (t >= off) ? part[t - off] : 0;
        __syncthreads();
        part[t] += w;
        __syncthreads();
    }
    int ex = boff[blockIdx.x] + part[t] - s;    // exclusive prefix of element `base`
    int2 o; o.x = ex; o.y = ex + u.x;
    *(int2*)(rowptr + base) = o;
    float2 dv;
    dv.x = rsqrtf((float)(u.x + 1));
    dv.y = rsqrtf((float)(u.y + 1));
    *(float2*)(dinv + base) = dv;
}

__global__ void k_fill(const void* __restrict__ eidx,
                       const int* __restrict__ rowptr, int* __restrict__ fillp,
                       int* __restrict__ col) {
    int i = blockIdx.x * 256 + threadIdx.x;
    if (i >= NE) return;
    int e64 = e64_of(eidx);
    int s = geti(eidx, (size_t)i, e64);
    int d = geti(eidx, (size_t)NE + i, e64);
    int p = rowptr[d] + atomicAdd(&fillp[d], 1);
    col[p] = s;
}

// ---------------- half-wave row load/store (16B/lane load, 32 lanes per row) ----------------
template<int D, int MODE>
__device__ __forceinline__ void load_row_hw(const void* h, int sn, int c0, float* v) {
    if constexpr (MODE == 2) {                       // fp32, EPL=4
        float4 u = *(const float4*)((const float*)h + (size_t)sn * D + c0);
        v[0] = u.x; v[1] = u.y; v[2] = u.z; v[3] = u.w;
    } else {                                         // fp8, EPL=16
        uint4 u = *(const uint4*)((const unsigned char*)h + (size_t)sn * D + c0);
        dec4f(u.x, v); dec4f(u.y, v + 4); dec4f(u.z, v + 8); dec4f(u.w, v + 12);
    }
}

template<int D, int EPL, bool FP8>
__device__ __forceinline__ void store_row_hw(void* out, int n, int c0, const float* v) {
    if constexpr (FP8) {                             // EPL=16 -> 16B fp8
        uint4 u;
        u.x = enc4(v[0], v[1], v[2], v[3]);
        u.y = enc4(v[4], v[5], v[6], v[7]);
        u.z = enc4(v[8], v[9], v[10], v[11]);
        u.w = enc4(v[12], v[13], v[14], v[15]);
        *(uint4*)((unsigned char*)out + (size_t)n * D + c0) = u;
    } else {                                         // bf16, EPL=4 -> 8B
        uint2 u; u.x = pack2(v[0], v[1]); u.y = pack2(v[2], v[3]);
        *(uint2*)((unsigned short*)out + (size_t)n * D + c0) = u;
    }
}

// ---------------- half-wave pull aggregation (CSR, fp32 reg accum, 2-edge unrolled) ----------------
template<int D, int IN_MODE, bool OUT_FP8>
__global__ __launch_bounds__(256) void k_agg_hw(
    const void* __restrict__ h,
    const int* __restrict__ rowptr, const int* __restrict__ col,
    const float* __restrict__ dinv,
    void* __restrict__ out)
{
    constexpr int EPL = (IN_MODE == 1) ? 16 : 4;
    const int n = (blockIdx.x * 256 + threadIdx.x) >> 5;
    const int lane = threadIdx.x & 31;
    const int c0 = lane * EPL;
    float dn = dinv[n];
    float acc[EPL], va[EPL], vb[EPL];

    load_row_hw<D, IN_MODE>(h, n, c0, va);    // self loop: weight dinv[n]^2
    float wsl = dn * dn;
#pragma unroll
    for (int i = 0; i < EPL; ++i) acc[i] = va[i] * wsl;

    int e = rowptr[n], e1 = rowptr[n + 1];
    for (; e + 2 <= e1; e += 2) {
        int sa = col[e], sb = col[e + 1];
        float wa = dinv[sa] * dn, wb = dinv[sb] * dn;
        load_row_hw<D, IN_MODE>(h, sa, c0, va);
        load_row_hw<D, IN_MODE>(h, sb, c0, vb);
#pragma unroll
        for (int i = 0; i < EPL; ++i) acc[i] += va[i] * wa + vb[i] * wb;
    }
    if (e < e1) {
        int sa = col[e];
        float wa = dinv[sa] * dn;
        load_row_hw<D, IN_MODE>(h, sa, c0, va);
#pragma unroll
        for (int i = 0; i < EPL; ++i) acc[i] += va[i] * wa;
    }
    store_row_hw<D, EPL, OUT_FP8>(out, n, c0, acc);
}

// ---------------- fused layer-3 aggregation + epilogue + mean pool ----------------
__global__ __launch_bounds__(256) void k_agg_pool(
    const unsigned short* __restrict__ T3,
    const int* __restrict__ rowptr, const int* __restrict__ col,
    const float* __restrict__ dinv,
    const float* __restrict__ b, const float* __restrict__ s, const float* __restrict__ t,
    const int* __restrict__ gstart, unsigned short* __restrict__ pooled)
{
    __shared__ float red[4][256];
    const int g = blockIdx.x;
    const int wave = threadIdx.x >> 6, lane = threadIdx.x & 63;
    const int c0 = lane * 4;
    const int r0 = gstart[g], r1 = gstart[g + 1];
    float p0 = 0, p1 = 0, p2 = 0, p3 = 0;
    const float bc0 = b[c0], bc1 = b[c0 + 1], bc2 = b[c0 + 2], bc3 = b[c0 + 3];
    const float sc0 = s[c0], sc1 = s[c0 + 1], sc2 = s[c0 + 2], sc3 = s[c0 + 3];
    const float tc0 = t[c0], tc1 = t[c0 + 1], tc2 = t[c0 + 2], tc3 = t[c0 + 3];

    for (int n = r0 + wave; n < r1; n += 4) {
        float dn = dinv[n];
        float a0, a1, a2, a3;
        {
            uint2 u = *(const uint2*)(T3 + (size_t)n * 256 + c0);
            float w = dn * dn;
            a0 = bfbits2f(u.x & 0xffffu) * w; a1 = bfbits2f(u.x >> 16) * w;
            a2 = bfbits2f(u.y & 0xffffu) * w; a3 = bfbits2f(u.y >> 16) * w;
        }
        int e = rowptr[n], e1 = rowptr[n + 1];
        for (; e + 2 <= e1; e += 2) {
            int sa = col[e], sb = col[e + 1];
            float wa = dinv[sa] * dn, wb = dinv[sb] * dn;
            uint2 ua = *(const uint2*)(T3 + (size_t)sa * 256 + c0);
            uint2 ub = *(const uint2*)(T3 + (size_t)sb * 256 + c0);
            a0 += bfbits2f(ua.x & 0xffffu) * wa + bfbits2f(ub.x & 0xffffu) * wb;
            a1 += bfbits2f(ua.x >> 16) * wa + bfbits2f(ub.x >> 16) * wb;
            a2 += bfbits2f(ua.y & 0xffffu) * wa + bfbits2f(ub.y & 0xffffu) * wb;
            a3 += bfbits2f(ua.y >> 16) * wa + bfbits2f(ub.y >> 16) * wb;
        }
        if (e < e1) {
            int sa = col[e];
            float wa = dinv[sa] * dn;
            uint2 ua = *(const uint2*)(T3 + (size_t)sa * 256 + c0);
            a0 += bfbits2f(ua.x & 0xffffu) * wa; a1 += bfbits2f(ua.x >> 16) * wa;
            a2 += bfbits2f(ua.y & 0xffffu) * wa; a3 += bfbits2f(ua.y >> 16) * wa;
        }
        // bn3(relu(a + b3))
        p0 += sc0 * fmaxf(a0 + bc0, 0.0f) + tc0;
        p1 += sc1 * fmaxf(a1 + bc1, 0.0f) + tc1;
        p2 += sc2 * fmaxf(a2 + bc2, 0.0f) + tc2;
        p3 += sc3 * fmaxf(a3 + bc3, 0.0f) + tc3;
    }
    red[wave][c0] = p0; red[wave][c0 + 1] = p1; red[wave][c0 + 2] = p2; red[wave][c0 + 3] = p3;
    __syncthreads();
    int ch = threadIdx.x;
    float tot = red[0][ch] + red[1][ch] + red[2][ch] + red[3][ch];
    __syncthreads();
    red[0][ch] = tot;
    __syncthreads();
    if (ch < 128) {
        int ccount = r1 - r0;
        float inv = 1.0f / (float)(ccount > 0 ? ccount : 1);
        pooled[(size_t)g * 256 + 2 * ch] = f2bfbits(red[0][2 * ch] * inv);
        pooled[(size_t)g * 256 + 2 * ch + 1] = f2bfbits(red[0][2 * ch + 1] * inv);
    }
}

// ---------------- MFMA GEMM (4-wave 128x128; MLP head; round-6-proven) ----------------
template<bool A_FP8, int CB, int OUT_MODE, bool RELU, bool HAS_BN, bool HAS_BIAS>
__global__ __launch_bounds__(256)
void k_gemm(const void* __restrict__ Aptr,
            const unsigned short* __restrict__ Wt,
            const float* __restrict__ bias,
            const float* __restrict__ s, const float* __restrict__ t,
            void* __restrict__ Cptr,
            int K, int Ncols)
{
    __shared__ __align__(16) unsigned short lB[2][2][128 * 32];
    __shared__ __align__(16) unsigned char  lA8[A_FP8 ? 2 : 1][A_FP8 ? 2 : 1][A_FP8 ? 128 * 32 : 16];
    __shared__ __align__(16) unsigned short lA16[A_FP8 ? 1 : 2][A_FP8 ? 1 : 2][A_FP8 ? 8 : 128 * 32];
    const int tid = threadIdx.x;
    const int id = blockIdx.x;
    const int hi = id >> 3;
    const int cblk = hi % CB;
    const int rblk = (hi / CB) * 8 + (id & 7);
    const int bm = rblk * 128;
    const int bn = cblk * 128;
    const int lane = tid & 63;
    const int wave = tid >> 6;
    const int wm = (wave >> 1) * 64;
    const int wn = (wave & 1) * 64;
    const int fr = lane & 15;
    const int fq = lane >> 4;

    f32x4 acc[4][4] = {};
    const int NG64 = K >> 6;

    auto stage = [&](int buf, int k0) {
#pragma unroll
        for (int h = 0; h < 2; ++h) {
            const int kh = k0 + h * 32;
            if constexpr (A_FP8) {
                const unsigned char* g = (const unsigned char*)Aptr
                    + (size_t)(bm + (wave << 5) + (lane >> 1)) * K + kh + (lane & 1) * 16;
                gld16(g, &lA8[buf][h][(wave << 5) * 32], lane);
            } else {
                const unsigned short* Ab = (const unsigned short*)Aptr;
#pragma unroll
                for (int c = 0; c < 2; ++c) {
                    const unsigned short* g = Ab
                        + (size_t)(bm + (wave << 5) + (c << 4) + (lane >> 2)) * K + kh + (lane & 3) * 8;
                    gld16(g, &lA16[buf][h][((wave << 5) + (c << 4)) * 32], lane);
                }
            }
#pragma unroll
            for (int c = 0; c < 2; ++c) {
                const unsigned short* g = Wt
                    + (size_t)(bn + (wave << 5) + (c << 4) + (lane >> 2)) * K + kh + (lane & 3) * 8;
                gld16(g, &lB[buf][h][((wave << 5) + (c << 4)) * 32], lane);
            }
        }
    };

    stage(0, 0);
    __syncthreads();

    int cur = 0;
    for (int kg = 0; kg < NG64; ++kg) {
        if (kg + 1 < NG64) stage(cur ^ 1, (kg + 1) << 6);

#pragma unroll
        for (int h = 0; h < 2; ++h) {
            short8 a[4], b[4];
#pragma unroll
            for (int i = 0; i < 4; ++i) {
                if constexpr (A_FP8)
                    a[i] = dec8(*(const uint2*)&lA8[cur][h][(wm + 16 * i + fr) * 32 + fq * 8]);
                else
                    a[i] = *(const short8*)&lA16[cur][h][(wm + 16 * i + fr) * 32 + fq * 8];
            }
#pragma unroll
            for (int j = 0; j < 4; ++j)
                b[j] = *(const short8*)&lB[cur][h][(wn + 16 * j + fr) * 32 + fq * 8];
#pragma unroll
            for (int i = 0; i < 4; ++i)
#pragma unroll
                for (int j = 0; j < 4; ++j)
                    acc[i][j] = __builtin_amdgcn_mfma_f32_16x16x32_bf16(a[i], b[j], acc[i][j], 0, 0, 0);
        }

        __syncthreads();
        cur ^= 1;
    }

#pragma unroll
    for (int j = 0; j < 4; ++j) {
        int colI = bn + wn + 16 * j + fr;
        float bi = HAS_BIAS ? bias[colI] : 0.0f;
        float sc = HAS_BN ? s[colI] : 1.0f;
        float tc = HAS_BN ? t[colI] : 0.0f;
#pragma unroll
        for (int i = 0; i < 4; ++i) {
#pragma unroll
            for (int r = 0; r < 4; ++r) {
                int row = bm + wm + 16 * i + fq * 4 + r;
                float z = acc[i][j][r] + bi;
                if (RELU) z = fmaxf(z, 0.0f);
                float y = HAS_BN ? (sc * z + tc) : z;
                if constexpr (OUT_MODE == 2)
                    ((float*)Cptr)[(size_t)row * Ncols + colI] = y;
                else if constexpr (OUT_MODE == 1)
                    ((unsigned char*)Cptr)[(size_t)row * Ncols + colI] = (unsigned char)enc1(y);
                else
                    ((unsigned short*)Cptr)[(size_t)row * Ncols + colI] = f2bfbits(y);
            }
        }
    }
}

// ---------------- 8-wave 256x128 fp8-A MFMA GEMM (GEMM2 + GEMM3; round-8-proven) ----------------
template<int CB, int OUT_MODE, bool RELU, bool HAS_BN, bool HAS_BIAS>
__global__ __launch_bounds__(512)
void k_gemm8w(const unsigned char* __restrict__ Aptr,
              const unsigned short* __restrict__ Wt,
              const float* __restrict__ bias,
              const float* __restrict__ s, const float* __restrict__ t,
              void* __restrict__ Cptr,
              int K, int Ncols)
{
    __shared__ __align__(16) unsigned char  lA[2][2][256 * 32];   // 32 KB fp8
    __shared__ __align__(16) unsigned short lB[2][2][128 * 32];   // 32 KB bf16
    const int tid = threadIdx.x;
    const int id = blockIdx.x;
    const int hi = id >> 3;
    const int cblk = hi % CB;
    const int rblk = (hi / CB) * 8 + (id & 7);
    const int bm = rblk * 256;
    const int bn = cblk * 128;
    const int lane = tid & 63;
    const int wave = tid >> 6;          // 0..7
    const int wm = (wave >> 1) * 64;    // 0,64,128,192
    const int wn = (wave & 1) * 64;     // 0,64
    const int fr = lane & 15;
    const int fq = lane >> 4;

    f32x4 acc[4][4] = {};
    const int NG64 = K >> 6;

    auto stage = [&](int buf, int k0) {
#pragma unroll
        for (int h = 0; h < 2; ++h) {
            const int kh = k0 + h * 32;
            {
                const unsigned char* g = Aptr
                    + (size_t)(bm + (wave << 5) + (lane >> 1)) * K + kh + (lane & 1) * 16;
                gld16(g, &lA[buf][h][(wave << 5) * 32], lane);
            }
            {
                const unsigned short* g = Wt
                    + (size_t)(bn + (wave << 4) + (lane >> 2)) * K + kh + (lane & 3) * 8;
                gld16(g, &lB[buf][h][(wave << 4) * 32], lane);
            }
        }
    };

    stage(0, 0);
    __syncthreads();

    int cur = 0;
    for (int kg = 0; kg < NG64; ++kg) {
        if (kg + 1 < NG64) stage(cur ^ 1, (kg + 1) << 6);

#pragma unroll
        for (int h = 0; h < 2; ++h) {
            short8 a[4], b[4];
#pragma unroll
            for (int i = 0; i < 4; ++i)
                a[i] = dec8(*(const uint2*)&lA[cur][h][(wm + 16 * i + fr) * 32 + fq * 8]);
#pragma unroll
            for (int j = 0; j < 4; ++j)
                b[j] = *(const short8*)&lB[cur][h][(wn + 16 * j + fr) * 32 + fq * 8];
#pragma unroll
            for (int i = 0; i < 4; ++i)
#pragma unroll
                for (int j = 0; j < 4; ++j)
                    acc[i][j] = __builtin_amdgcn_mfma_f32_16x16x32_bf16(a[i], b[j], acc[i][j], 0, 0, 0);
        }

        __syncthreads();
        cur ^= 1;
    }

#pragma unroll
    for (int j = 0; j < 4; ++j) {
        int colI = bn + wn + 16 * j + fr;
        float bi = HAS_BIAS ? bias[colI] : 0.0f;
        float sc = HAS_BN ? s[colI] : 1.0f;
        float tc = HAS_BN ? t[colI] : 0.0f;
#pragma unroll
        for (int i = 0; i < 4; ++i) {
#pragma unroll
            for (int r = 0; r < 4; ++r) {
                int row = bm + wm + 16 * i + fq * 4 + r;
                float z = acc[i][j][r] + bi;
                if (RELU) z = fmaxf(z, 0.0f);
                float y = HAS_BN ? (sc * z + tc) : z;
                if constexpr (OUT_MODE == 2)
                    ((float*)Cptr)[(size_t)row * Ncols + colI] = y;
                else if constexpr (OUT_MODE == 1)
                    ((unsigned char*)Cptr)[(size_t)row * Ncols + colI] = (unsigned char)enc1(y);
                else
                    ((unsigned short*)Cptr)[(size_t)row * Ncols + colI] = f2bfbits(y);
            }
        }
    }
}

// ---------------- 8-wave 128x128 bf16-A MFMA GEMM (GEMM1; round-9-proven) ----------------
template<int CB, int OUT_MODE, bool RELU, bool HAS_BN, bool HAS_BIAS>
__global__ __launch_bounds__(512)
void k_gemm8n(const unsigned short* __restrict__ Aptr,
              const unsigned short* __restrict__ Wt,
              const float* __restrict__ bias,
              const float* __restrict__ s, const float* __restrict__ t,
              void* __restrict__ Cptr,
              int K, int Ncols)
{
    __shared__ __align__(16) unsigned short lA[2][2][128 * 32];   // 32 KB
    __shared__ __align__(16) unsigned short lB[2][2][128 * 32];   // 32 KB
    const int tid = threadIdx.x;
    const int id = blockIdx.x;
    const int hi = id >> 3;
    const int cblk = hi % CB;
    const int rblk = (hi / CB) * 8 + (id & 7);
    const int bm = rblk * 128;
    const int bn = cblk * 128;
    const int lane = tid & 63;
    const int wave = tid >> 6;          // 0..7
    const int wm = (wave >> 1) * 32;    // 0,32,64,96
    const int wn = (wave & 1) * 64;     // 0,64
    const int fr = lane & 15;
    const int fq = lane >> 4;

    f32x4 acc[2][4] = {};
    const int NG64 = K >> 6;

    auto stage = [&](int buf, int k0) {
#pragma unroll
        for (int h = 0; h < 2; ++h) {
            const int kh = k0 + h * 32;
            const unsigned short* ga = Aptr
                + (size_t)(bm + (wave << 4) + (lane >> 2)) * K + kh + (lane & 3) * 8;
            gld16(ga, &lA[buf][h][(wave << 4) * 32], lane);
            const unsigned short* gb = Wt
                + (size_t)(bn + (wave << 4) + (lane >> 2)) * K + kh + (lane & 3) * 8;
            gld16(gb, &lB[buf][h][(wave << 4) * 32], lane);
        }
    };

    stage(0, 0);
    __syncthreads();

    int cur = 0;
    for (int kg = 0; kg < NG64; ++kg) {
        if (kg + 1 < NG64) stage(cur ^ 1, (kg + 1) << 6);

#pragma unroll
        for (int h = 0; h < 2; ++h) {
            short8 a[2], b[4];
#pragma unroll
            for (int i = 0; i < 2; ++i)
                a[i] = *(const short8*)&lA[cur][h][(wm + 16 * i + fr) * 32 + fq * 8];
#pragma unroll
            for (int j = 0; j < 4; ++j)
                b[j] = *(const short8*)&lB[cur][h][(wn + 16 * j + fr) * 32 + fq * 8];
#pragma unroll
            for (int i = 0; i < 2; ++i)
#pragma unroll
                for (int j = 0; j < 4; ++j)
                    acc[i][j] = __builtin_amdgcn_mfma_f32_16x16x32_bf16(a[i], b[j], acc[i][j], 0, 0, 0);
        }

        __syncthreads();
        cur ^= 1;
    }

#pragma unroll
    for (int j = 0; j < 4; ++j) {
        int colI = bn + wn + 16 * j + fr;
        float bi = HAS_BIAS ? bias[colI] : 0.0f;
        float sc = HAS_BN ? s[colI] : 1.0f;
        float tc = HAS_BN ? t[colI] : 0.0f;
#pragma unroll
        for (int i = 0; i < 2; ++i) {
#pragma unroll
            for (int r = 0; r < 4; ++r) {
                int row = bm + wm + 16 * i + fq * 4 + r;
                float z = acc[i][j][r] + bi;
                if (RELU) z = fmaxf(z, 0.0f);
                float y = HAS_BN ? (sc * z + tc) : z;
                if constexpr (OUT_MODE == 2)
                    ((float*)Cptr)[(size_t)row * Ncols + colI] = y;
                else if constexpr (OUT_MODE == 1)
                    ((unsigned char*)Cptr)[(size_t)row * Ncols + colI] = (unsigned char)enc1(y);
                else
                    ((unsigned short*)Cptr)[(size_t)row * Ncols + colI] = f2bfbits(y);
            }
        }
    }
}

// ---------------- launch ----------------

extern "C" void kernel_launch(void* const* d_in, const int* in_sizes, int n_in,
                              void* d_out, int out_size, void* d_ws, size_t ws_size,
                              hipStream_t stream) {
    const float* x   = (const float*)d_in[0];      // fp32 per reference
    const void* eidx = d_in[1];
    const void* batch = d_in[2];
    const float* W1  = (const float*)d_in[3];
    const float* b1  = (const float*)d_in[4];
    const float* W2  = (const float*)d_in[5];
    const float* b2  = (const float*)d_in[6];
    const float* W3  = (const float*)d_in[7];
    const float* b3  = (const float*)d_in[8];
    const float* g1  = (const float*)d_in[9];
    const float* be1 = (const float*)d_in[10];
    const float* m1  = (const float*)d_in[11];
    const float* v1  = (const float*)d_in[12];
    const float* g2  = (const float*)d_in[13];
    const float* be2 = (const float*)d_in[14];
    const float* m2  = (const float*)d_in[15];
    const float* v2  = (const float*)d_in[16];
    const float* g3  = (const float*)d_in[17];
    const float* be3 = (const float*)d_in[18];
    const float* m3  = (const float*)d_in[19];
    const float* v3  = (const float*)d_in[20];
    const float* Wf1 = (const float*)d_in[21];
    const float* bf1 = (const float*)d_in[22];
    const float* Wf2 = (const float*)d_in[23];
    const float* bf2 = (const float*)d_in[24];

    // ---- fixed compact layout (round-6-proven, ~139.6 MiB) ----
    unsigned char* RB = (unsigned char*)d_ws;            // 64 MiB: H1/H2 fp8 [NN,512]; later pooled/z1
    unsigned char* RA = RB + 67108864;                   // 64 MiB: agg1 bf16 / agg2 fp8 / T3 bf16
    unsigned char* EX = RB + 134217728;                  // extras ~5.4 MiB
    int*   rowptr = (int*)(EX + 0);
    int*   col    = (int*)(EX + 524544);
    float* dinv   = (float*)(EX + 2621696);
    int*   cnt    = (int*)(EX + 3145984);
    int*   fillp  = (int*)(EX + 3670272);   // contiguous after cnt (cnt is NN ints)
    int*   gstart = (int*)(EX + 4194560);
    float* sbuf   = (float*)(EX + 4211456);
    float *s1 = sbuf, *t1 = sbuf + 512, *s2 = sbuf + 1024, *t2 = sbuf + 1536;
    float *s3 = sbuf + 2048, *t3v = sbuf + 2304;
    unsigned short* Wt1  = (unsigned short*)(EX + 4221696);  // [512,128] bf16
    unsigned short* Wt2  = (unsigned short*)(EX + 4352768);  // [512,512]
    unsigned short* Wt3  = (unsigned short*)(EX + 4877056);  // [256,512]
    unsigned short* Wtf1 = (unsigned short*)(EX + 5139200);  // [256,256]
    unsigned short* Wtf2 = (unsigned short*)(EX + 5270272);  // [256,256]
    int*   bsum  = (int*)(EX + 5401344);    // [256] scan block sums
    int*   boff  = (int*)(EX + 5402368);    // [256] scan block offsets

    unsigned short* pooled = (unsigned short*)RB;            // [NG,256] bf16 (H2 dead after GEMM3)
    unsigned short* z1     = (unsigned short*)(RB + 2097152);

    // ---- prep: single merged kernel, then CSR build (3-phase multi-block scan) ----
    k_prep<<<3845, 256, 0, stream>>>(W1, W2, W3, Wf1, Wf2,
                                     Wt1, Wt2, Wt3, Wtf1, Wtf2,
                                     g1, be1, m1, v1, g2, be2, m2, v2, g3, be3, m3, v3,
                                     sbuf, cnt, batch, gstart);
    k_deg_count<<<NE / 256, 256, 0, stream>>>(eidx, cnt);
    k_scan_a<<<256, 256, 0, stream>>>(cnt, bsum);
    k_scan_b<<<1, 256, 0, stream>>>(bsum, boff, rowptr);
    k_scan_c<<<256, 256, 0, stream>>>(cnt, boff, rowptr, dinv);
    k_fill<<<NE / 256, 256, 0, stream>>>(eidx, rowptr, fillp, col);

    const dim3 gagg(NN / 8);   // one node per 32-lane half-wave

    // L1: agg x(fp32) @128 -> bf16 agg1 (RA); 8-wave GEMM 128->512 +bias+relu+bn -> H1 fp8 (RB)
    k_agg_hw<128, 2, false><<<gagg, 256, 0, stream>>>(x, rowptr, col, dinv, RA);
    k_gemm8n<4, 1, true, true, true><<<4096, 512, 0, stream>>>(
        (const unsigned short*)RA, Wt1, b1, s1, t1, RB, 128, 512);

    // L2: agg H1(fp8) @512 -> agg2 fp8 (RA); 8-wave GEMM 512->512 +epilogue -> H2 fp8 (RB)
    // kept split into two row-half dispatches (diagnostic visibility; cost ~0)
    k_agg_hw<512, 1, true><<<gagg, 256, 0, stream>>>(RB, rowptr, col, dinv, RA);
    k_gemm8w<4, 1, true, true, true><<<1024, 512, 0, stream>>>(RA, Wt2, b2, s2, t2, RB, 512, 512);
    k_gemm8w<4, 1, true, true, true><<<1024, 512, 0, stream>>>(RA + 33554432, Wt2, b2, s2, t2,
                                                               RB + 33554432, 512, 512);

    // L3: 8-wave GEMM 512->256 raw (H2 fp8 -> T3 bf16 in RA)
    k_gemm8w<2, 0, false, false, false><<<1024, 512, 0, stream>>>(RB, Wt3, nullptr, nullptr, nullptr, RA, 512, 256);

    // fused: agg @256 + bn3(relu(+b3)) + mean pool -> pooled bf16 (RB; H2 dead)
    k_agg_pool<<<NG, 256, 0, stream>>>((const unsigned short*)RA, rowptr, col, dinv,
                                       b3, s3, t3v, gstart, pooled);

    // MLP head: z1 = relu(pooled@Wf1 + bf1); out(fp32) = z1@Wf2 + bf2
    k_gemm<false, 2, 0, true, false, true><<<64, 256, 0, stream>>>(pooled, Wtf1, bf1, nullptr, nullptr, z1, 256, 256);
    k_gemm<false, 2, 2, false, false, true><<<64, 256, 0, stream>>>(z1, Wtf2, bf2, nullptr, nullptr, d_out, 256, 256);
}

// Round 12
// 551.034 us; speedup vs baseline: 1.1317x; 1.0224x over previous
//
#include <hip/hip_runtime.h>

static constexpr int NN = 131072;   // nodes
static constexpr int NE = 524288;   // edges
static constexpr int NG = 4096;     // graphs

typedef __attribute__((ext_vector_type(8))) short short8;
typedef __attribute__((ext_vector_type(4))) float f32x4;
typedef __attribute__((ext_vector_type(2))) float f32x2;

__device__ __forceinline__ float bfbits2f(unsigned b) {
    return __uint_as_float(b << 16);
}
__device__ __forceinline__ unsigned short f2bfbits(float f) {
    unsigned u = __float_as_uint(f);
    u += 0x7fffu + ((u >> 16) & 1u);   // RNE
    return (unsigned short)(u >> 16);
}
__device__ __forceinline__ unsigned pack2(float a, float b) {
    return (unsigned)f2bfbits(a) | ((unsigned)f2bfbits(b) << 16);
}

// dual-width integer read (robust to int32 or int64 index tensors)
__device__ __forceinline__ int geti(const void* p, size_t i, int w64) {
    return w64 ? (int)((const long long*)p)[i] : ((const int*)p)[i];
}
// inline int-width detect (sentinel words are chip-wide cached; ~free per thread)
__device__ __forceinline__ int e64_of(const void* eidx) {
    const int* e = (const int*)eidx;
    return (e[1] == 0 && e[2001] == 0 && e[40001] == 0 && e[2 * NE - 1] == 0) ? 1 : 0;
}
__device__ __forceinline__ int b64_of(const void* batch) {
    return (((const int*)batch)[NN - 1] == 0) ? 1 : 0;
}

#if __has_builtin(__builtin_amdgcn_cvt_pk_f32_fp8) && __has_builtin(__builtin_amdgcn_cvt_pk_fp8_f32)
#define FP8_CVT_HW 1
#else
#define FP8_CVT_HW 0
#endif

// ---- software OCP e4m3 codec (fallback) ----
__device__ __forceinline__ float e4m32f(unsigned b) {
    unsigned e = (b >> 3) & 0xFu, m = b & 7u;
    float v = e ? __uint_as_float(((e + 120u) << 23) | (m << 20))
                : (float)m * 0.001953125f;            // m * 2^-9
    return (b & 0x80u) ? -v : v;
}
__device__ __forceinline__ unsigned f2e4m3(float f) {
    unsigned u = __float_as_uint(f);
    unsigned s = (u >> 24) & 0x80u;
    unsigned mag = u & 0x7fffffffu;
    if (mag >= 0x43e00000u) return s | 0x7eu;          // clamp to +-448
    if (mag < 0x3c800000u) {                           // |f| < 2^-6 -> subnormal
        int q = (int)(__uint_as_float(mag) * 512.0f + 0.5f);   // 0..8
        return s | (unsigned)q;
    }
    unsigned r = mag + 0x0007ffffu + ((mag >> 20) & 1u);       // RNE to 3 mant bits
    if (r >= 0x43e00000u) return s | 0x7eu;
    return s | (((r >> 23) - 120u) << 3) | ((r >> 20) & 7u);
}

// 2 fp8 (byte pair HI of dword w) -> packed bf16 dword. HI must be immediate.
template<bool HI>
__device__ __forceinline__ unsigned dec_pair(unsigned w) {
#if FP8_CVT_HW
    f32x2 p = __builtin_amdgcn_cvt_pk_f32_fp8((int)w, HI);
    return __builtin_amdgcn_perm(__float_as_uint(p.y), __float_as_uint(p.x), 0x07060302u);
#else
    unsigned b0 = HI ? ((w >> 16) & 255u) : (w & 255u);
    unsigned b1 = HI ? (w >> 24) : ((w >> 8) & 255u);
    return pack2(e4m32f(b0), e4m32f(b1));
#endif
}

// 8 fp8 -> short8 bf16 fragment
__device__ __forceinline__ short8 dec8(uint2 u) {
    union { uint4 q; short8 s; } r;
    r.q.x = dec_pair<false>(u.x);
    r.q.y = dec_pair<true>(u.x);
    r.q.z = dec_pair<false>(u.y);
    r.q.w = dec_pair<true>(u.y);
    return r.s;
}

// 4 fp8 bytes of dword w -> 4 floats
__device__ __forceinline__ void dec4f(unsigned w, float* v) {
#if FP8_CVT_HW
    f32x2 a = __builtin_amdgcn_cvt_pk_f32_fp8((int)w, false);
    f32x2 b = __builtin_amdgcn_cvt_pk_f32_fp8((int)w, true);
    v[0] = a.x; v[1] = a.y; v[2] = b.x; v[3] = b.y;
#else
#pragma unroll
    for (int i = 0; i < 4; ++i) v[i] = e4m32f((w >> (8 * i)) & 0xffu);
#endif
}

__device__ __forceinline__ unsigned enc4(float a, float b, float c, float d) {
#if FP8_CVT_HW
    int r = __builtin_amdgcn_cvt_pk_fp8_f32(a, b, 0, false);
    r = __builtin_amdgcn_cvt_pk_fp8_f32(c, d, r, true);
    return (unsigned)r;
#else
    return f2e4m3(a) | (f2e4m3(b) << 8) | (f2e4m3(c) << 16) | (f2e4m3(d) << 24);
#endif
}
__device__ __forceinline__ unsigned enc1(float a) {
#if FP8_CVT_HW
    return (unsigned)__builtin_amdgcn_cvt_pk_fp8_f32(a, a, 0, false) & 0xffu;
#else
    return f2e4m3(a);
#endif
}

// 8 bf16 (uint4) -> 8 floats
__device__ __forceinline__ void bf8f(uint4 u, float* v) {
    v[0] = bfbits2f(u.x & 0xffffu); v[1] = bfbits2f(u.x >> 16);
    v[2] = bfbits2f(u.y & 0xffffu); v[3] = bfbits2f(u.y >> 16);
    v[4] = bfbits2f(u.z & 0xffffu); v[5] = bfbits2f(u.z >> 16);
    v[6] = bfbits2f(u.w & 0xffffu); v[7] = bfbits2f(u.w >> 16);
}

// async global->LDS, 16B/lane; data lands at l + lane*16
__device__ __forceinline__ void gld16(const void* g, void* l, int lane) {
#if __has_builtin(__builtin_amdgcn_global_load_lds)
    __builtin_amdgcn_global_load_lds((const __attribute__((address_space(1))) unsigned int*)g,
                                     (__attribute__((address_space(3))) unsigned int*)l, 16, 0, 0);
#else
    *(uint4*)((char*)l + lane * 16) = *(const uint4*)g;
#endif
}

// ---------------- merged prep kernel (transposes + bn + zero + gstart) ----------------
__global__ __launch_bounds__(256) void k_prep(
    const float* __restrict__ W1, const float* __restrict__ W2, const float* __restrict__ W3,
    const float* __restrict__ Wf1, const float* __restrict__ Wf2,
    unsigned short* __restrict__ Wt1, unsigned short* __restrict__ Wt2,
    unsigned short* __restrict__ Wt3, unsigned short* __restrict__ Wtf1,
    unsigned short* __restrict__ Wtf2,
    const float* __restrict__ g1, const float* __restrict__ be1,
    const float* __restrict__ m1, const float* __restrict__ v1,
    const float* __restrict__ g2, const float* __restrict__ be2,
    const float* __restrict__ m2, const float* __restrict__ v2,
    const float* __restrict__ g3, const float* __restrict__ be3,
    const float* __restrict__ m3, const float* __restrict__ v3,
    float* __restrict__ sbuf, int* __restrict__ cnt2,
    const void* __restrict__ batch, int* __restrict__ gstart)
{
    const int id = blockIdx.x, tid = threadIdx.x;
    if (id < 1024) {                         // W2 [512,512]
        int idx = id * 256 + tid; int k = idx >> 9, n = idx & 511;
        Wt2[n * 512 + k] = f2bfbits(W2[idx]);
    } else if (id < 1536) {                  // W3 [512,256]
        int idx = (id - 1024) * 256 + tid; int k = idx >> 8, n = idx & 255;
        Wt3[n * 512 + k] = f2bfbits(W3[idx]);
    } else if (id < 1792) {                  // W1 [128,512]
        int idx = (id - 1536) * 256 + tid; int k = idx >> 9, n = idx & 511;
        Wt1[n * 128 + k] = f2bfbits(W1[idx]);
    } else if (id < 2048) {                  // Wf1 [256,256]
        int idx = (id - 1792) * 256 + tid; int k = idx >> 8, n = idx & 255;
        Wtf1[n * 256 + k] = f2bfbits(Wf1[idx]);
    } else if (id < 2304) {                  // Wf2 [256,256]
        int idx = (id - 2048) * 256 + tid; int k = idx >> 8, n = idx & 255;
        Wtf2[n * 256 + k] = f2bfbits(Wf2[idx]);
    } else if (id < 3328) {                  // zero cnt + fillp (contiguous 2*NN ints)
        cnt2[(id - 2304) * 256 + tid] = 0;
    } else if (id < 3333) {                  // bn prep: 512+512+256 channels
        int i = (id - 3328) * 256 + tid;
        if (i < 512) {
            float inv = rsqrtf(v1[i] + 1e-5f); float sc = g1[i] * inv;
            sbuf[i] = sc; sbuf[512 + i] = be1[i] - m1[i] * sc;
        } else if (i < 1024) {
            int j = i - 512;
            float inv = rsqrtf(v2[j] + 1e-5f); float sc = g2[j] * inv;
            sbuf[1024 + j] = sc; sbuf[1536 + j] = be2[j] - m2[j] * sc;
        } else if (i < 1280) {
            int j = i - 1024;
            float inv = rsqrtf(v3[j] + 1e-5f); float sc = g3[j] * inv;
            sbuf[2048 + j] = sc; sbuf[2304 + j] = be3[j] - m3[j] * sc;
        }
    } else {                                 // gstart (batch sorted)
        int i = (id - 3333) * 256 + tid;
        if (i >= NN) return;
        int b64 = b64_of(batch);
        int b = geti(batch, (size_t)i, b64);
        if (i == 0) {
            for (int g = 0; g <= b; ++g) gstart[g] = 0;
        } else {
            int pb = geti(batch, (size_t)i - 1, b64);
            for (int g = pb + 1; g <= b; ++g) gstart[g] = i;
        }
        if (i == NN - 1) {
            for (int g = b + 1; g <= NG; ++g) gstart[g] = NN;
        }
    }
}

__global__ void k_deg_count(const void* __restrict__ eidx, int* __restrict__ cnt) {
    int i = blockIdx.x * 256 + threadIdx.x;
    if (i >= NE) return;
    int d = geti(eidx, (size_t)NE + i, e64_of(eidx));
    atomicAdd(&cnt[d], 1);
}

// ---------------- 3-phase multi-block scan ----------------
__global__ __launch_bounds__(256) void k_scan_a(const int* __restrict__ cnt, int* __restrict__ bsum) {
    __shared__ int red[256];
    const int t = threadIdx.x;
    int2 u = *(const int2*)(cnt + blockIdx.x * 512 + t * 2);
    red[t] = u.x + u.y;
    __syncthreads();
    for (int off = 128; off > 0; off >>= 1) {
        if (t < off) red[t] += red[t + off];
        __syncthreads();
    }
    if (t == 0) bsum[blockIdx.x] = red[0];
}

__global__ __launch_bounds__(256) void k_scan_b(const int* __restrict__ bsum, int* __restrict__ boff,
                                                int* __restrict__ rowptr) {
    __shared__ int part[256];
    const int t = threadIdx.x;
    int v = bsum[t];
    part[t] = v;
    __syncthreads();
    for (int off = 1; off < 256; off <<= 1) {
        int w = (t >= off) ? part[t - off] : 0;
        __syncthreads();
        part[t] += w;
        __syncthreads();
    }
    boff[t] = part[t] - v;   // exclusive
    if (t == 255) rowptr[NN] = part[255];
}

__global__ __launch_bounds__(256) void k_scan_c(const int* __restrict__ cnt, const int* __restrict__ boff,
                                                int* __restrict__ rowptr, float* __restrict__ dinv) {
    __shared__ int part[256];
    const int t = threadIdx.x;
    const int base = blockIdx.x * 512 + t * 2;
    int2 u = *(const int2*)(cnt + base);
    int s = u.x + u.y;
    part[t] = s;
    __syncthreads();
    for (int off = 1; off < 256; off <<= 1) {
        int w = (t >= off) ? part[t - off] : 0;
        __syncthreads();
        part[t] += w;
        __syncthreads();
    }
    int ex = boff[blockIdx.x] + part[t] - s;    // exclusive prefix of element `base`
    int2 o; o.x = ex; o.y = ex + u.x;
    *(int2*)(rowptr + base) = o;
    float2 dv;
    dv.x = rsqrtf((float)(u.x + 1));
    dv.y = rsqrtf((float)(u.y + 1));
    *(float2*)(dinv + base) = dv;
}

__global__ void k_fill(const void* __restrict__ eidx,
                       const int* __restrict__ rowptr, int* __restrict__ fillp,
                       int* __restrict__ col) {
    int i = blockIdx.x * 256 + threadIdx.x;
    if (i >= NE) return;
    int e64 = e64_of(eidx);
    int s = geti(eidx, (size_t)i, e64);
    int d = geti(eidx, (size_t)NE + i, e64);
    int p = rowptr[d] + atomicAdd(&fillp[d], 1);
    col[p] = s;
}

// ---------------- half-wave row load/store (16B/lane load, 32 lanes per row) ----------------
template<int D, int MODE>
__device__ __forceinline__ void load_row_hw(const void* h, int sn, int c0, float* v) {
    if constexpr (MODE == 2) {                       // fp32, EPL=4
        float4 u = *(const float4*)((const float*)h + (size_t)sn * D + c0);
        v[0] = u.x; v[1] = u.y; v[2] = u.z; v[3] = u.w;
    } else {                                         // fp8, EPL=16
        uint4 u = *(const uint4*)((const unsigned char*)h + (size_t)sn * D + c0);
        dec4f(u.x, v); dec4f(u.y, v + 4); dec4f(u.z, v + 8); dec4f(u.w, v + 12);
    }
}

template<int D, int EPL, bool FP8>
__device__ __forceinline__ void store_row_hw(void* out, int n, int c0, const float* v) {
    if constexpr (FP8) {                             // EPL=16 -> 16B fp8
        uint4 u;
        u.x = enc4(v[0], v[1], v[2], v[3]);
        u.y = enc4(v[4], v[5], v[6], v[7]);
        u.z = enc4(v[8], v[9], v[10], v[11]);
        u.w = enc4(v[12], v[13], v[14], v[15]);
        *(uint4*)((unsigned char*)out + (size_t)n * D + c0) = u;
    } else {                                         // bf16, EPL=4 -> 8B
        uint2 u; u.x = pack2(v[0], v[1]); u.y = pack2(v[2], v[3]);
        *(uint2*)((unsigned short*)out + (size_t)n * D + c0) = u;
    }
}

// ---------------- half-wave pull aggregation (CSR, fp32 reg accum, 2-edge unrolled) ----------------
template<int D, int IN_MODE, bool OUT_FP8>
__global__ __launch_bounds__(256) void k_agg_hw(
    const void* __restrict__ h,
    const int* __restrict__ rowptr, const int* __restrict__ col,
    const float* __restrict__ dinv,
    void* __restrict__ out)
{
    constexpr int EPL = (IN_MODE == 1) ? 16 : 4;
    const int n = (blockIdx.x * 256 + threadIdx.x) >> 5;
    const int lane = threadIdx.x & 31;
    const int c0 = lane * EPL;
    float dn = dinv[n];
    float acc[EPL], va[EPL], vb[EPL];

    load_row_hw<D, IN_MODE>(h, n, c0, va);    // self loop: weight dinv[n]^2
    float wsl = dn * dn;
#pragma unroll
    for (int i = 0; i < EPL; ++i) acc[i] = va[i] * wsl;

    int e = rowptr[n], e1 = rowptr[n + 1];
    for (; e + 2 <= e1; e += 2) {
        int sa = col[e], sb = col[e + 1];
        float wa = dinv[sa] * dn, wb = dinv[sb] * dn;
        load_row_hw<D, IN_MODE>(h, sa, c0, va);
        load_row_hw<D, IN_MODE>(h, sb, c0, vb);
#pragma unroll
        for (int i = 0; i < EPL; ++i) acc[i] += va[i] * wa + vb[i] * wb;
    }
    if (e < e1) {
        int sa = col[e];
        float wa = dinv[sa] * dn;
        load_row_hw<D, IN_MODE>(h, sa, c0, va);
#pragma unroll
        for (int i = 0; i < EPL; ++i) acc[i] += va[i] * wa;
    }
    store_row_hw<D, EPL, OUT_FP8>(out, n, c0, acc);
}

// ---------------- fused layer-3 aggregation + epilogue + mean pool (half-wave, 16B/lane) ----------------
// One node per 32-lane half-wave (G13, round-6-proven lever): uint4 = 8 bf16 per lane,
// 8 half-waves per block -> 2x independent gathers in flight, half the load instructions.
// Per-channel accumulation order unchanged; only the cross-partial pooled sum reassociates
// (8 partials vs 4) -> fp32 reorder noise ~1e-6, far inside absmax headroom.
__global__ __launch_bounds__(256) void k_agg_pool(
    const unsigned short* __restrict__ T3,
    const int* __restrict__ rowptr, const int* __restrict__ col,
    const float* __restrict__ dinv,
    const float* __restrict__ b, const float* __restrict__ s, const float* __restrict__ t,
    const int* __restrict__ gstart, unsigned short* __restrict__ pooled)
{
    __shared__ float red[8][256];
    const int g = blockIdx.x;
    const int hw = threadIdx.x >> 5, lane = threadIdx.x & 31;
    const int c0 = lane * 8;
    const int r0 = gstart[g], r1 = gstart[g + 1];
    float p[8] = {};
    float bc[8], sc[8], tc[8];
#pragma unroll
    for (int i = 0; i < 8; ++i) { bc[i] = b[c0 + i]; sc[i] = s[c0 + i]; tc[i] = t[c0 + i]; }

    for (int n = r0 + hw; n < r1; n += 8) {
        float dn = dinv[n];
        float a[8], va[8], vb[8];
        {
            uint4 u = *(const uint4*)(T3 + (size_t)n * 256 + c0);
            bf8f(u, a);
            float w = dn * dn;
#pragma unroll
            for (int i = 0; i < 8; ++i) a[i] *= w;
        }
        int e = rowptr[n], e1 = rowptr[n + 1];
        for (; e + 2 <= e1; e += 2) {
            int sa = col[e], sb = col[e + 1];
            float wa = dinv[sa] * dn, wb = dinv[sb] * dn;
            uint4 ua = *(const uint4*)(T3 + (size_t)sa * 256 + c0);
            uint4 ub = *(const uint4*)(T3 + (size_t)sb * 256 + c0);
            bf8f(ua, va); bf8f(ub, vb);
#pragma unroll
            for (int i = 0; i < 8; ++i) a[i] += va[i] * wa + vb[i] * wb;
        }
        if (e < e1) {
            int sa = col[e];
            float wa = dinv[sa] * dn;
            uint4 ua = *(const uint4*)(T3 + (size_t)sa * 256 + c0);
            bf8f(ua, va);
#pragma unroll
            for (int i = 0; i < 8; ++i) a[i] += va[i] * wa;
        }
        // bn3(relu(a + b3)) accumulated into pooled partial
#pragma unroll
        for (int i = 0; i < 8; ++i) p[i] += sc[i] * fmaxf(a[i] + bc[i], 0.0f) + tc[i];
    }
#pragma unroll
    for (int i = 0; i < 8; ++i) red[hw][c0 + i] = p[i];
    __syncthreads();
    int ch = threadIdx.x;
    float tot = red[0][ch] + red[1][ch] + red[2][ch] + red[3][ch]
              + red[4][ch] + red[5][ch] + red[6][ch] + red[7][ch];
    __syncthreads();
    red[0][ch] = tot;
    __syncthreads();
    if (ch < 128) {
        int ccount = r1 - r0;
        float inv = 1.0f / (float)(ccount > 0 ? ccount : 1);
        pooled[(size_t)g * 256 + 2 * ch] = f2bfbits(red[0][2 * ch] * inv);
        pooled[(size_t)g * 256 + 2 * ch + 1] = f2bfbits(red[0][2 * ch + 1] * inv);
    }
}

// ---------------- MFMA GEMM (4-wave 128x128; MLP head; round-6-proven) ----------------
template<bool A_FP8, int CB, int OUT_MODE, bool RELU, bool HAS_BN, bool HAS_BIAS>
__global__ __launch_bounds__(256)
void k_gemm(const void* __restrict__ Aptr,
            const unsigned short* __restrict__ Wt,
            const float* __restrict__ bias,
            const float* __restrict__ s, const float* __restrict__ t,
            void* __restrict__ Cptr,
            int K, int Ncols)
{
    __shared__ __align__(16) unsigned short lB[2][2][128 * 32];
    __shared__ __align__(16) unsigned char  lA8[A_FP8 ? 2 : 1][A_FP8 ? 2 : 1][A_FP8 ? 128 * 32 : 16];
    __shared__ __align__(16) unsigned short lA16[A_FP8 ? 1 : 2][A_FP8 ? 1 : 2][A_FP8 ? 8 : 128 * 32];
    const int tid = threadIdx.x;
    const int id = blockIdx.x;
    const int hi = id >> 3;
    const int cblk = hi % CB;
    const int rblk = (hi / CB) * 8 + (id & 7);
    const int bm = rblk * 128;
    const int bn = cblk * 128;
    const int lane = tid & 63;
    const int wave = tid >> 6;
    const int wm = (wave >> 1) * 64;
    const int wn = (wave & 1) * 64;
    const int fr = lane & 15;
    const int fq = lane >> 4;

    f32x4 acc[4][4] = {};
    const int NG64 = K >> 6;

    auto stage = [&](int buf, int k0) {
#pragma unroll
        for (int h = 0; h < 2; ++h) {
            const int kh = k0 + h * 32;
            if constexpr (A_FP8) {
                const unsigned char* g = (const unsigned char*)Aptr
                    + (size_t)(bm + (wave << 5) + (lane >> 1)) * K + kh + (lane & 1) * 16;
                gld16(g, &lA8[buf][h][(wave << 5) * 32], lane);
            } else {
                const unsigned short* Ab = (const unsigned short*)Aptr;
#pragma unroll
                for (int c = 0; c < 2; ++c) {
                    const unsigned short* g = Ab
                        + (size_t)(bm + (wave << 5) + (c << 4) + (lane >> 2)) * K + kh + (lane & 3) * 8;
                    gld16(g, &lA16[buf][h][((wave << 5) + (c << 4)) * 32], lane);
                }
            }
#pragma unroll
            for (int c = 0; c < 2; ++c) {
                const unsigned short* g = Wt
                    + (size_t)(bn + (wave << 5) + (c << 4) + (lane >> 2)) * K + kh + (lane & 3) * 8;
                gld16(g, &lB[buf][h][((wave << 5) + (c << 4)) * 32], lane);
            }
        }
    };

    stage(0, 0);
    __syncthreads();

    int cur = 0;
    for (int kg = 0; kg < NG64; ++kg) {
        if (kg + 1 < NG64) stage(cur ^ 1, (kg + 1) << 6);

#pragma unroll
        for (int h = 0; h < 2; ++h) {
            short8 a[4], b[4];
#pragma unroll
            for (int i = 0; i < 4; ++i) {
                if constexpr (A_FP8)
                    a[i] = dec8(*(const uint2*)&lA8[cur][h][(wm + 16 * i + fr) * 32 + fq * 8]);
                else
                    a[i] = *(const short8*)&lA16[cur][h][(wm + 16 * i + fr) * 32 + fq * 8];
            }
#pragma unroll
            for (int j = 0; j < 4; ++j)
                b[j] = *(const short8*)&lB[cur][h][(wn + 16 * j + fr) * 32 + fq * 8];
#pragma unroll
            for (int i = 0; i < 4; ++i)
#pragma unroll
                for (int j = 0; j < 4; ++j)
                    acc[i][j] = __builtin_amdgcn_mfma_f32_16x16x32_bf16(a[i], b[j], acc[i][j], 0, 0, 0);
        }

        __syncthreads();
        cur ^= 1;
    }

#pragma unroll
    for (int j = 0; j < 4; ++j) {
        int colI = bn + wn + 16 * j + fr;
        float bi = HAS_BIAS ? bias[colI] : 0.0f;
        float sc = HAS_BN ? s[colI] : 1.0f;
        float tc = HAS_BN ? t[colI] : 0.0f;
#pragma unroll
        for (int i = 0; i < 4; ++i) {
#pragma unroll
            for (int r = 0; r < 4; ++r) {
                int row = bm + wm + 16 * i + fq * 4 + r;
                float z = acc[i][j][r] + bi;
                if (RELU) z = fmaxf(z, 0.0f);
                float y = HAS_BN ? (sc * z + tc) : z;
                if constexpr (OUT_MODE == 2)
                    ((float*)Cptr)[(size_t)row * Ncols + colI] = y;
                else if constexpr (OUT_MODE == 1)
                    ((unsigned char*)Cptr)[(size_t)row * Ncols + colI] = (unsigned char)enc1(y);
                else
                    ((unsigned short*)Cptr)[(size_t)row * Ncols + colI] = f2bfbits(y);
            }
        }
    }
}

// ---------------- 8-wave 256x128 fp8-A MFMA GEMM (GEMM2 + GEMM3; round-8-proven) ----------------
template<int CB, int OUT_MODE, bool RELU, bool HAS_BN, bool HAS_BIAS>
__global__ __launch_bounds__(512)
void k_gemm8w(const unsigned char* __restrict__ Aptr,
              const unsigned short* __restrict__ Wt,
              const float* __restrict__ bias,
              const float* __restrict__ s, const float* __restrict__ t,
              void* __restrict__ Cptr,
              int K, int Ncols)
{
    __shared__ __align__(16) unsigned char  lA[2][2][256 * 32];   // 32 KB fp8
    __shared__ __align__(16) unsigned short lB[2][2][128 * 32];   // 32 KB bf16
    const int tid = threadIdx.x;
    const int id = blockIdx.x;
    const int hi = id >> 3;
    const int cblk = hi % CB;
    const int rblk = (hi / CB) * 8 + (id & 7);
    const int bm = rblk * 256;
    const int bn = cblk * 128;
    const int lane = tid & 63;
    const int wave = tid >> 6;          // 0..7
    const int wm = (wave >> 1) * 64;    // 0,64,128,192
    const int wn = (wave & 1) * 64;     // 0,64
    const int fr = lane & 15;
    const int fq = lane >> 4;

    f32x4 acc[4][4] = {};
    const int NG64 = K >> 6;

    auto stage = [&](int buf, int k0) {
#pragma unroll
        for (int h = 0; h < 2; ++h) {
            const int kh = k0 + h * 32;
            {
                const unsigned char* g = Aptr
                    + (size_t)(bm + (wave << 5) + (lane >> 1)) * K + kh + (lane & 1) * 16;
                gld16(g, &lA[buf][h][(wave << 5) * 32], lane);
            }
            {
                const unsigned short* g = Wt
                    + (size_t)(bn + (wave << 4) + (lane >> 2)) * K + kh + (lane & 3) * 8;
                gld16(g, &lB[buf][h][(wave << 4) * 32], lane);
            }
        }
    };

    stage(0, 0);
    __syncthreads();

    int cur = 0;
    for (int kg = 0; kg < NG64; ++kg) {
        if (kg + 1 < NG64) stage(cur ^ 1, (kg + 1) << 6);

#pragma unroll
        for (int h = 0; h < 2; ++h) {
            short8 a[4], b[4];
#pragma unroll
            for (int i = 0; i < 4; ++i)
                a[i] = dec8(*(const uint2*)&lA[cur][h][(wm + 16 * i + fr) * 32 + fq * 8]);
#pragma unroll
            for (int j = 0; j < 4; ++j)
                b[j] = *(const short8*)&lB[cur][h][(wn + 16 * j + fr) * 32 + fq * 8];
#pragma unroll
            for (int i = 0; i < 4; ++i)
#pragma unroll
                for (int j = 0; j < 4; ++j)
                    acc[i][j] = __builtin_amdgcn_mfma_f32_16x16x32_bf16(a[i], b[j], acc[i][j], 0, 0, 0);
        }

        __syncthreads();
        cur ^= 1;
    }

#pragma unroll
    for (int j = 0; j < 4; ++j) {
        int colI = bn + wn + 16 * j + fr;
        float bi = HAS_BIAS ? bias[colI] : 0.0f;
        float sc = HAS_BN ? s[colI] : 1.0f;
        float tc = HAS_BN ? t[colI] : 0.0f;
#pragma unroll
        for (int i = 0; i < 4; ++i) {
#pragma unroll
            for (int r = 0; r < 4; ++r) {
                int row = bm + wm + 16 * i + fq * 4 + r;
                float z = acc[i][j][r] + bi;
                if (RELU) z = fmaxf(z, 0.0f);
                float y = HAS_BN ? (sc * z + tc) : z;
                if constexpr (OUT_MODE == 2)
                    ((float*)Cptr)[(size_t)row * Ncols + colI] = y;
                else if constexpr (OUT_MODE == 1)
                    ((unsigned char*)Cptr)[(size_t)row * Ncols + colI] = (unsigned char)enc1(y);
                else
                    ((unsigned short*)Cptr)[(size_t)row * Ncols + colI] = f2bfbits(y);
            }
        }
    }
}

// ---------------- 8-wave 128x128 bf16-A MFMA GEMM (GEMM1; round-9-proven) ----------------
template<int CB, int OUT_MODE, bool RELU, bool HAS_BN, bool HAS_BIAS>
__global__ __launch_bounds__(512)
void k_gemm8n(const unsigned short* __restrict__ Aptr,
              const unsigned short* __restrict__ Wt,
              const float* __restrict__ bias,
              const float* __restrict__ s, const float* __restrict__ t,
              void* __restrict__ Cptr,
              int K, int Ncols)
{
    __shared__ __align__(16) unsigned short lA[2][2][128 * 32];   // 32 KB
    __shared__ __align__(16) unsigned short lB[2][2][128 * 32];   // 32 KB
    const int tid = threadIdx.x;
    const int id = blockIdx.x;
    const int hi = id >> 3;
    const int cblk = hi % CB;
    const int rblk = (hi / CB) * 8 + (id & 7);
    const int bm = rblk * 128;
    const int bn = cblk * 128;
    const int lane = tid & 63;
    const int wave = tid >> 6;          // 0..7
    const int wm = (wave >> 1) * 32;    // 0,32,64,96
    const int wn = (wave & 1) * 64;     // 0,64
    const int fr = lane & 15;
    const int fq = lane >> 4;

    f32x4 acc[2][4] = {};
    const int NG64 = K >> 6;

    auto stage = [&](int buf, int k0) {
#pragma unroll
        for (int h = 0; h < 2; ++h) {
            const int kh = k0 + h * 32;
            const unsigned short* ga = Aptr
                + (size_t)(bm + (wave << 4) + (lane >> 2)) * K + kh + (lane & 3) * 8;
            gld16(ga, &lA[buf][h][(wave << 4) * 32], lane);
            const unsigned short* gb = Wt
                + (size_t)(bn + (wave << 4) + (lane >> 2)) * K + kh + (lane & 3) * 8;
            gld16(gb, &lB[buf][h][(wave << 4) * 32], lane);
        }
    };

    stage(0, 0);
    __syncthreads();

    int cur = 0;
    for (int kg = 0; kg < NG64; ++kg) {
        if (kg + 1 < NG64) stage(cur ^ 1, (kg + 1) << 6);

#pragma unroll
        for (int h = 0; h < 2; ++h) {
            short8 a[2], b[4];
#pragma unroll
            for (int i = 0; i < 2; ++i)
                a[i] = *(const short8*)&lA[cur][h][(wm + 16 * i + fr) * 32 + fq * 8];
#pragma unroll
            for (int j = 0; j < 4; ++j)
                b[j] = *(const short8*)&lB[cur][h][(wn + 16 * j + fr) * 32 + fq * 8];
#pragma unroll
            for (int i = 0; i < 2; ++i)
#pragma unroll
                for (int j = 0; j < 4; ++j)
                    acc[i][j] = __builtin_amdgcn_mfma_f32_16x16x32_bf16(a[i], b[j], acc[i][j], 0, 0, 0);
        }

        __syncthreads();
        cur ^= 1;
    }

#pragma unroll
    for (int j = 0; j < 4; ++j) {
        int colI = bn + wn + 16 * j + fr;
        float bi = HAS_BIAS ? bias[colI] : 0.0f;
        float sc = HAS_BN ? s[colI] : 1.0f;
        float tc = HAS_BN ? t[colI] : 0.0f;
#pragma unroll
        for (int i = 0; i < 2; ++i) {
#pragma unroll
            for (int r = 0; r < 4; ++r) {
                int row = bm + wm + 16 * i + fq * 4 + r;
                float z = acc[i][j][r] + bi;
                if (RELU) z = fmaxf(z, 0.0f);
                float y = HAS_BN ? (sc * z + tc) : z;
                if constexpr (OUT_MODE == 2)
                    ((float*)Cptr)[(size_t)row * Ncols + colI] = y;
                else if constexpr (OUT_MODE == 1)
                    ((unsigned char*)Cptr)[(size_t)row * Ncols + colI] = (unsigned char)enc1(y);
                else
                    ((unsigned short*)Cptr)[(size_t)row * Ncols + colI] = f2bfbits(y);
            }
        }
    }
}

// ---------------- launch ----------------

extern "C" void kernel_launch(void* const* d_in, const int* in_sizes, int n_in,
                              void* d_out, int out_size, void* d_ws, size_t ws_size,
                              hipStream_t stream) {
    const float* x   = (const float*)d_in[0];      // fp32 per reference
    const void* eidx = d_in[1];
    const void* batch = d_in[2];
    const float* W1  = (const float*)d_in[3];
    const float* b1  = (const float*)d_in[4];
    const float* W2  = (const float*)d_in[5];
    const float* b2  = (const float*)d_in[6];
    const float* W3  = (const float*)d_in[7];
    const float* b3  = (const float*)d_in[8];
    const float* g1  = (const float*)d_in[9];
    const float* be1 = (const float*)d_in[10];
    const float* m1  = (const float*)d_in[11];
    const float* v1  = (const float*)d_in[12];
    const float* g2  = (const float*)d_in[13];
    const float* be2 = (const float*)d_in[14];
    const float* m2  = (const float*)d_in[15];
    const float* v2  = (const float*)d_in[16];
    const float* g3  = (const float*)d_in[17];
    const float* be3 = (const float*)d_in[18];
    const float* m3  = (const float*)d_in[19];
    const float* v3  = (const float*)d_in[20];
    const float* Wf1 = (const float*)d_in[21];
    const float* bf1 = (const float*)d_in[22];
    const float* Wf2 = (const float*)d_in[23];
    const float* bf2 = (const float*)d_in[24];

    // ---- fixed compact layout (round-6-proven, ~139.6 MiB) ----
    unsigned char* RB = (unsigned char*)d_ws;            // 64 MiB: H1/H2 fp8 [NN,512]; later pooled/z1
    unsigned char* RA = RB + 67108864;                   // 64 MiB: agg1 bf16 / agg2 fp8 / T3 bf16
    unsigned char* EX = RB + 134217728;                  // extras ~5.4 MiB
    int*   rowptr = (int*)(EX + 0);
    int*   col    = (int*)(EX + 524544);
    float* dinv   = (float*)(EX + 2621696);
    int*   cnt    = (int*)(EX + 3145984);
    int*   fillp  = (int*)(EX + 3670272);   // contiguous after cnt (cnt is NN ints)
    int*   gstart = (int*)(EX + 4194560);
    float* sbuf   = (float*)(EX + 4211456);
    float *s1 = sbuf, *t1 = sbuf + 512, *s2 = sbuf + 1024, *t2 = sbuf + 1536;
    float *s3 = sbuf + 2048, *t3v = sbuf + 2304;
    unsigned short* Wt1  = (unsigned short*)(EX + 4221696);  // [512,128] bf16
    unsigned short* Wt2  = (unsigned short*)(EX + 4352768);  // [512,512]
    unsigned short* Wt3  = (unsigned short*)(EX + 4877056);  // [256,512]
    unsigned short* Wtf1 = (unsigned short*)(EX + 5139200);  // [256,256]
    unsigned short* Wtf2 = (unsigned short*)(EX + 5270272);  // [256,256]
    int*   bsum  = (int*)(EX + 5401344);    // [256] scan block sums
    int*   boff  = (int*)(EX + 5402368);    // [256] scan block offsets

    unsigned short* pooled = (unsigned short*)RB;            // [NG,256] bf16 (H2 dead after GEMM3)
    unsigned short* z1     = (unsigned short*)(RB + 2097152);

    // ---- prep: single merged kernel, then CSR build (3-phase multi-block scan) ----
    k_prep<<<3845, 256, 0, stream>>>(W1, W2, W3, Wf1, Wf2,
                                     Wt1, Wt2, Wt3, Wtf1, Wtf2,
                                     g1, be1, m1, v1, g2, be2, m2, v2, g3, be3, m3, v3,
                                     sbuf, cnt, batch, gstart);
    k_deg_count<<<NE / 256, 256, 0, stream>>>(eidx, cnt);
    k_scan_a<<<256, 256, 0, stream>>>(cnt, bsum);
    k_scan_b<<<1, 256, 0, stream>>>(bsum, boff, rowptr);
    k_scan_c<<<256, 256, 0, stream>>>(cnt, boff, rowptr, dinv);
    k_fill<<<NE / 256, 256, 0, stream>>>(eidx, rowptr, fillp, col);

    const dim3 gagg(NN / 8);   // one node per 32-lane half-wave

    // L1: agg x(fp32) @128 -> bf16 agg1 (RA); 8-wave GEMM 128->512 +bias+relu+bn -> H1 fp8 (RB)
    k_agg_hw<128, 2, false><<<gagg, 256, 0, stream>>>(x, rowptr, col, dinv, RA);
    k_gemm8n<4, 1, true, true, true><<<4096, 512, 0, stream>>>(
        (const unsigned short*)RA, Wt1, b1, s1, t1, RB, 128, 512);

    // L2: agg H1(fp8) @512 -> agg2 fp8 (RA); 8-wave GEMM 512->512 +epilogue -> H2 fp8 (RB)
    // kept split into two row-half dispatches (diagnostic visibility; cost ~0)
    k_agg_hw<512, 1, true><<<gagg, 256, 0, stream>>>(RB, rowptr, col, dinv, RA);
    k_gemm8w<4, 1, true, true, true><<<1024, 512, 0, stream>>>(RA, Wt2, b2, s2, t2, RB, 512, 512);
    k_gemm8w<4, 1, true, true, true><<<1024, 512, 0, stream>>>(RA + 33554432, Wt2, b2, s2, t2,
                                                               RB + 33554432, 512, 512);

    // L3: 8-wave GEMM 512->256 raw (H2 fp8 -> T3 bf16 in RA)
    k_gemm8w<2, 0, false, false, false><<<1024, 512, 0, stream>>>(RB, Wt3, nullptr, nullptr, nullptr, RA, 512, 256);

    // fused: agg @256 + bn3(relu(+b3)) + mean pool -> pooled bf16 (RB; H2 dead)
    k_agg_pool<<<NG, 256, 0, stream>>>((const unsigned short*)RA, rowptr, col, dinv,
                                       b3, s3, t3v, gstart, pooled);

    // MLP head: z1 = relu(pooled@Wf1 + bf1); out(fp32) = z1@Wf2 + bf2
    k_gemm<false, 2, 0, true, false, true><<<64, 256, 0, stream>>>(pooled, Wtf1, bf1, nullptr, nullptr, z1, 256, 256);
    k_gemm<false, 2, 2, false, false, true><<<64, 256, 0, stream>>>(z1, Wtf2, bf2, nullptr, nullptr, d_out, 256, 256);
}